// Round 8
// baseline (3636.201 us; speedup 1.0000x reference)
//
#include <hip/hip_runtime.h>
#include <cstdint>

typedef __bf16 bf16;
typedef __bf16 bf16x8 __attribute__((ext_vector_type(8)));
typedef __bf16 bf16x4 __attribute__((ext_vector_type(4)));
typedef short  s16x8  __attribute__((ext_vector_type(8)));
typedef float  f32x4  __attribute__((ext_vector_type(4)));

#define DEV __device__ __forceinline__

static const int LL = 4096, HH = 1024, NCH = 128;

DEV float b2f(bf16 x){ return (float)x; }
DEV bf16  f2b(float x){ return (bf16)x; }
DEV f32x4 mfma16(s16x8 a, s16x8 b, f32x4 c){
  return __builtin_amdgcn_mfma_f32_16x16x32_bf16(a, b, c, 0, 0, 0);
}
DEV s16x8 ldg8(const bf16* p){ return *(const s16x8*)p; }

// async global->LDS, 16B per lane (CK idiom: int->as(3)/as(1) via uintptr_t, no addrspacecast)
DEV void gld16(const bf16* g, bf16* l){
  auto* lp = reinterpret_cast<__attribute__((address_space(3))) uint32_t*>(
      reinterpret_cast<uintptr_t>(l));
  auto* gp = reinterpret_cast<const __attribute__((address_space(1))) uint32_t*>(
      reinterpret_cast<uintptr_t>(g));
  __builtin_amdgcn_global_load_lds(gp, lp, 16, 0, 0);
}

// single-wave LDS handoff: lgkmcnt drain + scheduling fence (rule #18).
// NOT __syncthreads(): hipcc prepends s_waitcnt vmcnt(0) to s_barrier, which would
// drain the cross-chunk global prefetch (R2 post-mortem: 22.5K cyc/chunk of exposed latency).
#define LDS_FENCE() do { asm volatile("s_waitcnt lgkmcnt(0)" ::: "memory"); \
                         __builtin_amdgcn_sched_barrier(0); } while(0)

// ---------------- hs f32 -> bf16 (once; all GEMM A-reads become bf16) ----------------
__global__ __launch_bounds__(256) void k_h2b(const float* __restrict__ X, bf16* __restrict__ Y){
  size_t i = ((size_t)blockIdx.x*256 + threadIdx.x)*8;
  float4 a = *(const float4*)(X+i), b = *(const float4*)(X+i+4);
  bf16x8 v;
  v[0]=f2b(a.x); v[1]=f2b(a.y); v[2]=f2b(a.z); v[3]=f2b(a.w);
  v[4]=f2b(b.x); v[5]=f2b(b.y); v[6]=f2b(b.z); v[7]=f2b(b.w);
  *(bf16x8*)(Y+i) = v;
}

// ---------------- weight transpose: W[K][N] f32 -> WT[N][K] bf16 hi + lo ----------------
__global__ __launch_bounds__(256) void k_wT(const float* __restrict__ W, bf16* __restrict__ Th,
                                            bf16* __restrict__ Tl, int K, int N){
  __shared__ float Ts[32][33];
  int t = threadIdx.x;
  int ni = blockIdx.x*32, ki = blockIdx.y*32;
  int r = t>>3, c4 = (t&7)*4;
  float4 v = *(const float4*)(W + (size_t)(ki+r)*N + ni + c4);
  Ts[r][c4+0]=v.x; Ts[r][c4+1]=v.y; Ts[r][c4+2]=v.z; Ts[r][c4+3]=v.w;
  __syncthreads();
  bf16x4 hh, llo;
  #pragma unroll
  for(int i=0;i<4;i++){
    float x = Ts[c4+i][r];
    bf16 hb = f2b(x); hh[i]=hb; llo[i]=f2b(x-(float)hb);
  }
  *(bf16x4*)(Th + (size_t)(ni+r)*K + ki + c4) = hh;
  *(bf16x4*)(Tl + (size_t)(ni+r)*K + ki + c4) = llo;
}

// ---------------- MFMA GEMM v2: A bf16 [M][K]; B as BT[N][K] bf16 hi/lo ----------------
// Double-buffered LDS staged by global_load_lds(16B): 1 barrier per K-step (its implicit
// vmcnt(0) drains the *next* tile's stage, issued before this step's compute -> overlap).
// Swizzle (rule #21): LDS dest linear (gload_lds requirement), global SOURCE column
// pre-XOR'd, read XOR'd: slot(row,cb') holds global colblk cb'^(row&3); reader of g uses
// cb'=g^(row&3) -> fetches g. XOR is an involution within the 64B row => bijective.
template<int EPI, int OF32>
__global__ __launch_bounds__(256) void k_gemm_m2(const bf16* __restrict__ A,
    const bf16* __restrict__ BTh, const bf16* __restrict__ BTl,
    const float* __restrict__ bias, void* __restrict__ Cp, int M, int N, int K){
  __shared__ __align__(16) bf16 As [2][128*32];
  __shared__ __align__(16) bf16 Bsh[2][128*32];
  __shared__ __align__(16) bf16 Bsl[2][128*32];
  int t = threadIdx.x;
  int w = t>>6, ln = t&63, lr = ln&15, lk = ln>>4;
  int wr = w>>1, wc = w&1;
  int m0 = blockIdx.y*128, n0 = blockIdx.x*128;
  f32x4 acc[4][4];
  #pragma unroll
  for(int m=0;m<4;m++)
    #pragma unroll
    for(int n=0;n<4;n++) acc[m][n] = f32x4{0.f,0.f,0.f,0.f};
  // stage geometry: per wave 2 instrs/array, instr j covers rows w*32+j*16 .. +15
  int srow[2], gcb[2];
  #pragma unroll
  for(int j=0;j<2;j++){
    srow[j] = w*32 + j*16 + (ln>>2);
    gcb[j]  = (ln&3) ^ (srow[j]&3);        // pre-swizzled source column block
  }
  auto STAGE = [&](int buf, int k0){
    #pragma unroll
    for(int j=0;j<2;j++){
      bf16* lb = &As[buf][(w*32+j*16)*32];  // wave-uniform base; HW adds lane*16
      gld16(A   + (size_t)(m0+srow[j])*K + k0 + gcb[j]*8, lb);
      lb = &Bsh[buf][(w*32+j*16)*32];
      gld16(BTh + (size_t)(n0+srow[j])*K + k0 + gcb[j]*8, lb);
      lb = &Bsl[buf][(w*32+j*16)*32];
      gld16(BTl + (size_t)(n0+srow[j])*K + k0 + gcb[j]*8, lb);
    }
  };
  STAGE(0, 0);
  __syncthreads();
  int cur = 0;
  for(int k0=0;k0<K;k0+=32){
    if(k0+32<K) STAGE(cur^1, k0+32);
    s16x8 a[4], bh[4], bl[4];
    #pragma unroll
    for(int m=0;m<4;m++){
      int row = wr*64 + m*16 + lr;
      a[m] = *(const s16x8*)((char*)As[cur] + row*64 + ((lk*16) ^ ((lr&3)<<4)));
    }
    #pragma unroll
    for(int n=0;n<4;n++){
      int row = wc*64 + n*16 + lr;
      int off = row*64 + ((lk*16) ^ ((lr&3)<<4));
      bh[n] = *(const s16x8*)((char*)Bsh[cur] + off);
      bl[n] = *(const s16x8*)((char*)Bsl[cur] + off);
    }
    #pragma unroll
    for(int m=0;m<4;m++)
      #pragma unroll
      for(int n=0;n<4;n++){
        acc[m][n] = mfma16(a[m], bh[n], acc[m][n]);
        acc[m][n] = mfma16(a[m], bl[n], acc[m][n]);
      }
    __syncthreads();   // drains vmcnt(0): next buffer fully staged; reads of cur done
    cur ^= 1;
  }
  #pragma unroll
  for(int m=0;m<4;m++)
    #pragma unroll
    for(int n=0;n<4;n++)
      #pragma unroll
      for(int r=0;r<4;r++){
        int gm = m0 + wr*64 + m*16 + lk*4 + r;
        int gn = n0 + wc*64 + n*16 + lr;
        float v = acc[m][n][r];
        if(EPI==1){ v += bias[gn]; v = 0.5f*v*(1.f + erff(v*0.70710678118f)); }
        if(OF32) ((float*)Cp)[(size_t)gm*N + gn] = v;
        else     ((bf16*)Cp)[(size_t)gm*N + gn] = f2b(v);
      }
}

// ---------------- beta = sigmoid(hs @ Wb), hs f32 ----------------
__global__ __launch_bounds__(256) void k_beta(const float* __restrict__ X, const float* __restrict__ Wb,
                                              float* __restrict__ beta){
  int row = blockIdx.x*4 + (threadIdx.x>>6), lane = threadIdx.x&63;
  const float* xp = X + (size_t)row*HH;
  float a0=0,a1=0,a2=0,a3=0;
  for(int k=lane;k<HH;k+=64){
    float x = xp[k];
    float4 wr = *(const float4*)(Wb + (size_t)k*4);
    a0 += x*wr.x; a1 += x*wr.y; a2 += x*wr.z; a3 += x*wr.w;
  }
  #pragma unroll
  for(int off=32;off>=1;off>>=1){
    a0 += __shfl_down(a0,off,64); a1 += __shfl_down(a1,off,64);
    a2 += __shfl_down(a2,off,64); a3 += __shfl_down(a3,off,64);
  }
  if(lane==0){
    beta[(size_t)row*4+0] = 1.f/(1.f+__expf(-a0));
    beta[(size_t)row*4+1] = 1.f/(1.f+__expf(-a1));
    beta[(size_t)row*4+2] = 1.f/(1.f+__expf(-a2));
    beta[(size_t)row*4+3] = 1.f/(1.f+__expf(-a3));
  }
}

// ---------------- depthwise causal conv K=4 + silu (+ per-head l2norm) ----------------
__global__ __launch_bounds__(256) void k_conv4(const bf16* __restrict__ pre, const float* __restrict__ filt,
                                               bf16* __restrict__ outp, int do_norm){
  __shared__ float red[4][8];
  int tx = threadIdx.x, head = blockIdx.y, b = blockIdx.z; int l0 = blockIdx.x*64;
  int wv = tx>>6, lane = tx&63;
  int c = head*256 + tx;
  const bf16* p = pre + (size_t)b*LL*HH + c;
  const float* fp = filt + (size_t)c*4;
  float f0=fp[0], f1=fp[1], f2=fp[2], f3=fp[3];
  float x0,x1,x2;
  if(l0>0){ x0=b2f(p[(size_t)(l0-3)*HH]); x1=b2f(p[(size_t)(l0-2)*HH]); x2=b2f(p[(size_t)(l0-1)*HH]); }
  else { x0=x1=x2=0.f; }
  for(int g=0; g<8; g++){
    float y[8];
    #pragma unroll
    for(int i=0;i<8;i++){
      int l = l0+g*8+i;
      float x3 = b2f(p[(size_t)l*HH]);
      float u = f0*x0 + f1*x1 + f2*x2 + f3*x3;
      x0=x1; x1=x2; x2=x3;
      y[i] = u/(1.f+__expf(-u));
    }
    if(do_norm){
      float sq[8];
      #pragma unroll
      for(int i=0;i<8;i++) sq[i]=y[i]*y[i];
      #pragma unroll
      for(int off=32;off>=1;off>>=1)
        #pragma unroll
        for(int i=0;i<8;i++) sq[i] += __shfl_down(sq[i],off,64);
      if(lane==0){
        #pragma unroll
        for(int i=0;i<8;i++) red[wv][i]=sq[i];
      }
      __syncthreads();
      float tot[8];
      #pragma unroll
      for(int i=0;i<8;i++) tot[i]=red[0][i]+red[1][i]+red[2][i]+red[3][i];
      __syncthreads();
      #pragma unroll
      for(int i=0;i<8;i++) y[i] *= rsqrtf(tot[i]);
    }
    #pragma unroll
    for(int i=0;i<8;i++) outp[(size_t)(b*LL + l0+g*8+i)*HH + c] = f2b(y[i]);
  }
}

// ---------------- gate: softmax4(h1 @ Wf2 + bf2), Wf2 f32 [2048][16] ----------------
__global__ __launch_bounds__(256) void k_gate(const bf16* __restrict__ h1, const float* __restrict__ W2,
                                              const float* __restrict__ bf2v, float* __restrict__ fw){
  int row = blockIdx.x*4 + (threadIdx.x>>6), lane = threadIdx.x&63;
  const bf16* hp = h1 + (size_t)row*2048;
  float acc[16];
  #pragma unroll
  for(int c=0;c<16;c++) acc[c]=0.f;
  for(int k=lane;k<2048;k+=64){
    float x = b2f(hp[k]);
    const float* wr = W2 + (size_t)k*16;
    float4 w0 = *(const float4*)(wr), w1 = *(const float4*)(wr+4);
    float4 w2 = *(const float4*)(wr+8), w3 = *(const float4*)(wr+12);
    acc[0]+=x*w0.x; acc[1]+=x*w0.y; acc[2]+=x*w0.z; acc[3]+=x*w0.w;
    acc[4]+=x*w1.x; acc[5]+=x*w1.y; acc[6]+=x*w1.z; acc[7]+=x*w1.w;
    acc[8]+=x*w2.x; acc[9]+=x*w2.y; acc[10]+=x*w2.z; acc[11]+=x*w2.w;
    acc[12]+=x*w3.x; acc[13]+=x*w3.y; acc[14]+=x*w3.z; acc[15]+=x*w3.w;
  }
  #pragma unroll
  for(int off=32;off>=1;off>>=1)
    #pragma unroll
    for(int c=0;c<16;c++) acc[c] += __shfl_down(acc[c],off,64);
  if(lane==0){
    #pragma unroll
    for(int h=0;h<4;h++){
      float s0=acc[h*4+0]+bf2v[h*4+0], s1=acc[h*4+1]+bf2v[h*4+1];
      float s2=acc[h*4+2]+bf2v[h*4+2], s3=acc[h*4+3]+bf2v[h*4+3];
      float mx = fmaxf(fmaxf(s0,s1),fmaxf(s2,s3));
      float e0=__expf(s0-mx), e1=__expf(s1-mx), e2=__expf(s2-mx), e3=__expf(s3-mx);
      float inv = 1.f/(e0+e1+e2+e3);
      fw[(size_t)row*16+h*4+0]=e0*inv; fw[(size_t)row*16+h*4+1]=e1*inv;
      fw[(size_t)row*16+h*4+2]=e2*inv; fw[(size_t)row*16+h*4+3]=e3*inv;
    }
  }
}

// ---------------- per-chunk precompute (VALU): T, u, w, attn(bf16 hi/lo), kT ----------------
__global__ __launch_bounds__(256) void k_pre2(const bf16* __restrict__ qn, const bf16* __restrict__ kn,
    const bf16* __restrict__ vv, const float* __restrict__ beta,
    bf16* __restrict__ uFb, bf16* __restrict__ wFb, bf16* __restrict__ aFb, bf16* __restrict__ aFl,
    bf16* __restrict__ kTb){
  __shared__ __align__(16) bf16 qs[8192], ks[8192], vs[8192];
  __shared__ float T[32][33];
  __shared__ float bet[32];
  int ch = blockIdx.x, bh = blockIdx.y, b = bh>>2, h = bh&3;
  int t = threadIdx.x;
  int l0 = ch*32;
  size_t rowbase = ((size_t)(b*LL+l0))*HH + h*256;
  #pragma unroll
  for(int i=0;i<4;i++){
    int f = i*256+t, row = f>>5, sub = f&31;
    size_t go = rowbase + (size_t)row*HH + sub*8;
    *(bf16x8*)&qs[f*8] = *(const bf16x8*)(qn+go);
    *(bf16x8*)&ks[f*8] = *(const bf16x8*)(kn+go);
    *(bf16x8*)&vs[f*8] = *(const bf16x8*)(vv+go);
  }
  if(t<32) bet[t] = beta[(size_t)(b*LL+l0+t)*4 + h];
  __syncthreads();
  int c = t>>3, e0 = (t&7)*4;
  float d0=0,d1=0,d2=0,d3=0, a0=0,a1=0,a2=0,a3=0;
  for(int d=0; d<256; d++){
    float kc = b2f(ks[c*256+d]);
    float qc = b2f(qs[c*256+d]);
    float k0 = b2f(ks[(e0+0)*256+d]);
    float k1 = b2f(ks[(e0+1)*256+d]);
    float k2 = b2f(ks[(e0+2)*256+d]);
    float k3 = b2f(ks[(e0+3)*256+d]);
    d0 += kc*k0; d1 += kc*k1; d2 += kc*k2; d3 += kc*k3;
    a0 += qc*k0; a1 += qc*k1; a2 += qc*k2; a3 += qc*k3;
  }
  float bc = bet[c];
  T[c][e0+0] = (c>e0+0)? -bc*d0 : 0.f;
  T[c][e0+1] = (c>e0+1)? -bc*d1 : 0.f;
  T[c][e0+2] = (c>e0+2)? -bc*d2 : 0.f;
  T[c][e0+3] = (c>e0+3)? -bc*d3 : 0.f;
  size_t ab = ((size_t)(bh*NCH+ch))*1024;
  {
    float av[4] = { (c>=e0+0)? a0 : 0.f, (c>=e0+1)? a1 : 0.f,
                    (c>=e0+2)? a2 : 0.f, (c>=e0+3)? a3 : 0.f };
    #pragma unroll
    for(int i=0;i<4;i++){
      bf16 hb = f2b(av[i]);
      aFb[ab + c*32 + e0+i] = hb;
      aFl[ab + c*32 + e0+i] = f2b(av[i] - (float)hb);
    }
  }
  __syncthreads();
  // forward substitution — lanes 0..31 of wave 0, lockstep; volatile forces LDS traffic
  if(t < 32){
    volatile float (*Tv)[33] = (volatile float (*)[33])T;
    int j = t;
    for(int i=1;i<32;i++){
      float s2 = 0.f;
      for(int m=0;m<i;m++) s2 += Tv[i][m]*Tv[m][j];
      Tv[i][j] += s2;
    }
    Tv[j][j] += 1.f;
  }
  __syncthreads();
  int dv0 = (t&7)*32;
  float uacc[32], wacc[32];
  #pragma unroll
  for(int j=0;j<32;j++){ uacc[j]=0.f; wacc[j]=0.f; }
  for(int c2=0;c2<32;c2++){
    float coef = T[c][c2]*bet[c2];
    #pragma unroll
    for(int j=0;j<32;j++){
      uacc[j] += coef * b2f(vs[c2*256+dv0+j]);
      wacc[j] += coef * b2f(ks[c2*256+dv0+j]);
    }
  }
  size_t ub = ((size_t)(bh*NCH+ch))*8192 + (size_t)c*256 + dv0;
  #pragma unroll
  for(int j=0;j<32;j++){ uFb[ub+j] = f2b(uacc[j]); wFb[ub+j] = f2b(wacc[j]); }
  // kT emit: thread t owns dk=t, writes kT[dk][0..31] (A-operand layout for S-update MFMA)
  {
    bf16* kout = kTb + ((size_t)(bh*NCH+ch))*8192 + (size_t)t*32;
    #pragma unroll
    for(int q8=0;q8<4;q8++){
      bf16x8 v8;
      #pragma unroll
      for(int i=0;i<8;i++) v8[i] = ks[(q8*8+i)*256 + t];
      *(bf16x8*)(kout + q8*8) = v8;
    }
  }
}

// ---------------- MFMA chunkwise scan v5: 8 waves/block for 2 waves/SIMD (TLP) ----------------
// R7 post-mortem: 6040 cyc/chunk vs ~1450 issue cycles => ~75% stall, and 128 single-wave
// blocks = 1 wave/SIMD => nothing fills stalls. Fix: co-locate 8 j-slice units of one bh
// in a 512-thread block (wave i -> SIMD i%4 => 2 waves/SIMD). Waves stay fully independent
// (own S state, own LDS slice, no __syncthreads); kernel body is unchanged from k_scan4.
// Bonus: all 8 waves read IDENTICAL w/kT/attn streams (j-independent) -> 8-way L1 reuse.
// LDS: 8 x 18432 B = 147456 B static (gfx950 LDS addressable = 160 KiB).
__global__ __launch_bounds__(512,2) void k_scan5(const bf16* __restrict__ qn,
    const bf16* __restrict__ wFb, const bf16* __restrict__ uFb,
    const bf16* __restrict__ kTb, const bf16* __restrict__ aFb, const bf16* __restrict__ aFl,
    bf16* __restrict__ delta){
  __shared__ __align__(16) char LDSall[8][18432];  // per wave: STh(8K) STl(8K) UTh(1K) UTl(1K)
  int tid = threadIdx.x;
  int wid = tid>>6, l = tid&63;
  char* STh = LDSall[wid];
  char* STl = STh + 8192;
  char* UTh = STh + 16384;
  char* UTl = STh + 17408;
  // blocks 0..15: bh = id&7 (blocks b and b+8 share bh and, round-robin, an XCD L2)
  int bh = blockIdx.x & 7, js = (blockIdx.x>>3)*8 + wid;
  int b = bh>>2, h = bh&3;
  int lr = l & 15, lk = l >> 4;
  int jb = js*16;
  float4 z4 = make_float4(0.f,0.f,0.f,0.f);
  #pragma unroll
  for(int i=0;i<8;i++){ ((float4*)STh)[l+i*64] = z4; ((float4*)STl)[l+i*64] = z4; }
  LDS_FENCE();
  f32x4 Sacc[16];
  #pragma unroll
  for(int i=0;i<16;i++) Sacc[i] = f32x4{0.f,0.f,0.f,0.f};
  const int Xst = (lr&7)<<4;   // ST row swizzle (bits 4-6 of FULL in-row byte offset, rule #21)
  const int Xut = (lr&3)<<4;   // UT row swizzle (bits 4-5)
  const bf16* wp  = wFb + (size_t)bh*NCH*8192;
  const bf16* up  = uFb + (size_t)bh*NCH*8192;
  const bf16* kp  = kTb + (size_t)bh*NCH*8192;
  const bf16* aph = aFb + (size_t)bh*NCH*1024;
  const bf16* apl = aFl + (size_t)bh*NCH*1024;
  const bf16* qp  = qn + (size_t)b*LL*HH + h*256;
  // prefetch registers (chunk 0)
  s16x8 Wr[16], Qr[16], Kr[16], A0h, A1h, A0l, A1l;
  bf16 Ur[8];
  #pragma unroll
  for(int t8=0;t8<8;t8++){
    Wr[t8]   = ldg8(wp + lr*256      + t8*32 + lk*8);
    Wr[8+t8] = ldg8(wp + (16+lr)*256 + t8*32 + lk*8);
    Qr[t8]   = ldg8(qp + (size_t)lr*HH      + t8*32 + lk*8);
    Qr[8+t8] = ldg8(qp + (size_t)(16+lr)*HH + t8*32 + lk*8);
  }
  #pragma unroll
  for(int dt=0;dt<16;dt++) Kr[dt] = ldg8(kp + (dt*16+lr)*32 + lk*8);
  A0h = ldg8(aph + lr*32 + lk*8); A1h = ldg8(aph + (16+lr)*32 + lk*8);
  A0l = ldg8(apl + lr*32 + lk*8); A1l = ldg8(apl + (16+lr)*32 + lk*8);
  #pragma unroll
  for(int r8=0;r8<8;r8++){
    int rr = (r8>>2)*16 + lk*4 + (r8&3);
    Ur[r8] = up[(size_t)rr*256 + jb + lr];
  }
  for(int ci=0; ci<NCH; ci++){
    size_t nxw = (ci<NCH-1)? 8192 : 0;            // next-chunk strides (clamped at tail)
    size_t nxa = (ci<NCH-1)? 1024 : 0;
    size_t nxq = (ci<NCH-1)? (size_t)32*HH : 0;
    // ---- Phase 1: ST fragments to regs, then the 64-MFMA block
    s16x8 sth[8], stl[8];
    #pragma unroll
    for(int t8=0;t8<8;t8++){
      int ro = lr*512 + ((t8*64 + lk*16) ^ Xst);
      sth[t8] = *(const s16x8*)(STh + ro);
      stl[t8] = *(const s16x8*)(STl + ro);
    }
    f32x4 wh0={0.f,0.f,0.f,0.f}, wl0=wh0, wh1=wh0, wl1=wh0;
    f32x4 qh0=wh0, ql0=wh0, qh1=wh0, ql1=wh0;
    #pragma unroll
    for(int t8=0;t8<8;t8++){
      wh0 = mfma16(Wr[t8],   sth[t8], wh0); wl0 = mfma16(Wr[t8],   stl[t8], wl0);
      wh1 = mfma16(Wr[8+t8], sth[t8], wh1); wl1 = mfma16(Wr[8+t8], stl[t8], wl1);
      qh0 = mfma16(Qr[t8],   sth[t8], qh0); ql0 = mfma16(Qr[t8],   stl[t8], ql0);
      qh1 = mfma16(Qr[8+t8], sth[t8], qh1); ql1 = mfma16(Qr[8+t8], stl[t8], ql1);
    }
    f32x4 ws0 = wh0+wl0, ws1 = wh1+wl1;
    f32x4 qs0 = qh0+ql0, qs1 = qh1+ql1;
    // prefetch next W,Q (regs fully consumed above)
    #pragma unroll
    for(int t8=0;t8<8;t8++){
      Wr[t8]   = ldg8(wp + nxw + lr*256      + t8*32 + lk*8);
      Wr[8+t8] = ldg8(wp + nxw + (16+lr)*256 + t8*32 + lk*8);
      Qr[t8]   = ldg8(qp + nxq + (size_t)lr*HH      + t8*32 + lk*8);
      Qr[8+t8] = ldg8(qp + nxq + (size_t)(16+lr)*HH + t8*32 + lk*8);
    }
    // ---- Phase 2: u_t = u - wS -> UT hi/lo (lane holds (c=ct*16+lk*4+r, j=lr))
    #pragma unroll
    for(int ct=0;ct<2;ct++){
      f32x4 w = ct? ws1 : ws0;
      bf16x4 hh, llo;
      #pragma unroll
      for(int r=0;r<4;r++){
        float v = b2f(Ur[ct*4+r]) - w[r];
        bf16 hb = f2b(v); hh[r]=hb; llo[r]=f2b(v-(float)hb);
      }
      int utw = lr*64 + ((ct*32 + lk*8) ^ Xut);
      *(bf16x4*)(UTh+utw)=hh; *(bf16x4*)(UTl+utw)=llo;
    }
    #pragma unroll
    for(int r8=0;r8<8;r8++){
      int rr = (r8>>2)*16 + lk*4 + (r8&3);
      Ur[r8] = up[nxw + (size_t)rr*256 + jb + lr];
    }
    LDS_FENCE();   // cross-lane UT handoff (wave-local lgkmcnt; no barrier)
    int utR = lr*64 + ((lk*16) ^ Xut);
    s16x8 th = *(const s16x8*)(UTh + utR);
    s16x8 tl = *(const s16x8*)(UTl + utR);
    // ---- Phase 3: o = qS + attn@u_t
    qs0 = mfma16(A0h, th, qs0); qs0 = mfma16(A0h, tl, qs0); qs0 = mfma16(A0l, th, qs0);
    qs1 = mfma16(A1h, th, qs1); qs1 = mfma16(A1h, tl, qs1); qs1 = mfma16(A1l, th, qs1);
    bf16* dp = delta + ((size_t)(b*LL + ci*32))*HH + h*256 + jb + lr;
    #pragma unroll
    for(int ct=0;ct<2;ct++){
      f32x4 o = ct? qs1 : qs0;
      #pragma unroll
      for(int r=0;r<4;r++) dp[(size_t)(ct*16 + lk*4 + r)*HH] = f2b(o[r]);
    }
    A0h = ldg8(aph + nxa + lr*32 + lk*8); A1h = ldg8(aph + nxa + (16+lr)*32 + lk*8);
    A0l = ldg8(apl + nxa + lr*32 + lk*8); A1l = ldg8(apl + nxa + (16+lr)*32 + lk*8);
    // ---- Phase 4: S[dk][j] += k^T @ u_t
    #pragma unroll
    for(int dt=0;dt<16;dt++){
      Sacc[dt] = mfma16(Kr[dt], th, Sacc[dt]);
      Sacc[dt] = mfma16(Kr[dt], tl, Sacc[dt]);
    }
    #pragma unroll
    for(int dt=0;dt<16;dt++) Kr[dt] = ldg8(kp + nxw + (size_t)(dt*16+lr)*32 + lk*8);
    // ---- Phase 5: restage S -> LDS bf16 hi/lo
    #pragma unroll
    for(int dt=0;dt<16;dt++){
      bf16x4 hh, llo;
      #pragma unroll
      for(int r=0;r<4;r++){
        float v = Sacc[dt][r];
        bf16 hb=f2b(v); hh[r]=hb; llo[r]=f2b(v-(float)hb);
      }
      int stw = lr*512 + ((dt*32 + lk*8) ^ Xst);
      *(bf16x4*)(STh+stw)=hh; *(bf16x4*)(STl+stw)=llo;
    }
    LDS_FENCE();   // S restage visible before next chunk's phase-1 reads
    wp += nxw; up += nxw; kp += nxw; aph += nxa; apl += nxa; qp += nxq;
  }
}

// ---------------- FIR convs + gated fusion + RMSNorm ----------------
__global__ __launch_bounds__(256) void k_fuse(const bf16* __restrict__ vv, const bf16* __restrict__ delta,
    const float* __restrict__ fw, const float* __restrict__ fsw, const float* __restrict__ flw,
    const float* __restrict__ rmsw, bf16* __restrict__ fused){
  __shared__ float red[4][8];
  int tx = threadIdx.x, head = blockIdx.y, b = blockIdx.z; int l0 = blockIdx.x*64;
  int wv = tx>>6, lane = tx&63;
  int c = head*256 + tx;
  const bf16* vp = vv + (size_t)b*LL*HH + c;
  float fs[7], fl[64];
  #pragma unroll
  for(int j=0;j<7;j++) fs[j] = fsw[(size_t)c*7+j];
  #pragma unroll
  for(int j=0;j<64;j++) fl[j] = flw[(size_t)c*64+j];
  float win[64];
  #pragma unroll
  for(int i=0;i<63;i++){ int l=l0-63+i; win[i] = (l>=0)? b2f(vp[(size_t)l*HH]) : 0.f; }
  float rw = rmsw[tx];
  for(int g=0; g<8; g++){
    float oo[8], sq[8];
    #pragma unroll
    for(int i=0;i<8;i++){
      int s = g*8+i; int l = l0+s;
      win[(s+63)&63] = b2f(vp[(size_t)l*HH]);
      float ll2 = 0.f;
      #pragma unroll
      for(int tp=0;tp<64;tp++) ll2 += fl[tp]*win[(s+tp)&63];
      float ls = 0.f;
      #pragma unroll
      for(int tp=0;tp<7;tp++) ls += fs[tp]*win[(s+57+tp)&63];
      float dl = b2f(delta[(size_t)(b*LL+l)*HH + c]);
      float vh = win[(s+63)&63];
      const float* fp = fw + (size_t)(b*LL+l)*16 + head*4;
      float o = fp[0]*ls + fp[1]*ll2 + fp[2]*dl + fp[3]*vh;
      oo[i]=o; sq[i]=o*o;
    }
    #pragma unroll
    for(int off=32;off>=1;off>>=1)
      #pragma unroll
      for(int i=0;i<8;i++) sq[i] += __shfl_down(sq[i],off,64);
    if(lane==0){
      #pragma unroll
      for(int i=0;i<8;i++) red[wv][i]=sq[i];
    }
    __syncthreads();
    float tot[8];
    #pragma unroll
    for(int i=0;i<8;i++) tot[i]=red[0][i]+red[1][i]+red[2][i]+red[3][i];
    __syncthreads();
    #pragma unroll
    for(int i=0;i<8;i++){
      int l = l0+g*8+i;
      fused[(size_t)(b*LL+l)*HH + c] = f2b(oo[i]*rsqrtf(tot[i]*(1.f/256.f)+1e-5f)*rw);
    }
  }
}

extern "C" void kernel_launch(void* const* d_in, const int* in_sizes, int n_in,
                              void* d_out, int out_size, void* d_ws, size_t ws_size,
                              hipStream_t stream){
  const float* hs  =(const float*)d_in[0];
  const float* Wq  =(const float*)d_in[1];
  const float* Wk  =(const float*)d_in[2];
  const float* Wv  =(const float*)d_in[3];
  const float* Wb  =(const float*)d_in[4];
  const float* cqw =(const float*)d_in[5];
  const float* ckw =(const float*)d_in[6];
  const float* cvw =(const float*)d_in[7];
  const float* fsw =(const float*)d_in[8];
  const float* flw =(const float*)d_in[9];
  const float* Wf1 =(const float*)d_in[10];
  const float* bf1 =(const float*)d_in[11];
  const float* Wf2 =(const float*)d_in[12];
  const float* bf2v=(const float*)d_in[13];
  const float* rmsw=(const float*)d_in[14];
  const float* Wo  =(const float*)d_in[15];

  char* ws = (char*)d_ws;
  size_t off = 0;
  auto alloc = [&](size_t bytes)->char*{
    char* p = ws + off; off = (off + bytes + 255) & ~(size_t)255; return p;
  };
  bf16* pre   = (bf16*)alloc(8192ull*1024*2);   // q/k/v pre-conv (sequential); later kTb; later fusedb
  bf16* qn    = (bf16*)alloc(8192ull*1024*2);
  bf16* kn    = (bf16*)alloc(8192ull*1024*2);
  bf16* vvb   = (bf16*)alloc(8192ull*1024*2);
  float* beta = (float*)alloc(8192ull*4*4);
  bf16* uFb   = (bf16*)alloc(8ull*128*8192*2);  // h1 aliases uFb+wFb (32MB) before k_pre2
  bf16* wFb   = (bf16*)alloc(8ull*128*8192*2);
  bf16* aFb   = (bf16*)alloc(8ull*128*1024*4);  // hi (2MB) + lo (2MB) attn, bf16
  float* fw   = (float*)alloc(8192ull*16*4);
  bf16* aFl   = aFb + 8ull*128*1024;
  bf16* h1    = uFb;                            // dead once fw extracted
  bf16* kTb   = pre;                            // pre dead after conv-v; dead again before k_fuse
  bf16* dlt   = (bf16*)d_out;                   // first 16MB of the 32MB f32 out; dead before final GEMM
  bf16* fusedb= pre;
  float* outb = (float*)d_out;
  // aliased staging (no extra workspace):
  //  - hsb (bf16 hs, 16MB): vvb-space — vvb is only written by conv-v, the LAST hs consumer ran
  //  - WT(Wf1) 8MB: qn-space (qn written by conv-q, after the gate GEMM)
  //  - WT(Wq/Wk/Wv/Wo) 4MB: uFb-space (dead between k_gate and k_pre2, and after k_scan4)
  bf16* hsb  = vvb;
  bf16* WT1h = qn;            bf16* WT1l = qn + 2048ull*1024;
  bf16* WTh  = uFb;           bf16* WTl  = uFb + 1024ull*1024;

  dim3 b256(256);
  // hs -> bf16 once
  k_h2b<<<dim3(4096), b256, 0, stream>>>(hs, hsb);
  // gate path FIRST (h1 aliases uFb/wFb; WT(Wf1) lives in qn-space)
  k_wT<<<dim3(64,32), b256, 0, stream>>>(Wf1, WT1h, WT1l, 1024, 2048);
  k_gemm_m2<1,0><<<dim3(16,64), b256, 0, stream>>>(hsb, WT1h, WT1l, bf1, h1, 8192, 2048, 1024);
  k_gate<<<dim3(2048), b256, 0, stream>>>(h1, Wf2, bf2v, fw);
  // q path (WT in uFb-space, dead until k_pre2)
  k_wT<<<dim3(32,32), b256, 0, stream>>>(Wq, WTh, WTl, 1024, 1024);
  k_gemm_m2<0,0><<<dim3(8,64), b256, 0, stream>>>(hsb, WTh, WTl, nullptr, pre, 8192, 1024, 1024);
  k_conv4<<<dim3(64,4,2), b256, 0, stream>>>(pre, cqw, qn, 1);
  // k path
  k_wT<<<dim3(32,32), b256, 0, stream>>>(Wk, WTh, WTl, 1024, 1024);
  k_gemm_m2<0,0><<<dim3(8,64), b256, 0, stream>>>(hsb, WTh, WTl, nullptr, pre, 8192, 1024, 1024);
  k_conv4<<<dim3(64,4,2), b256, 0, stream>>>(pre, ckw, kn, 1);
  // v path (last hsb use, then conv-v overwrites hsb with vvb)
  k_wT<<<dim3(32,32), b256, 0, stream>>>(Wv, WTh, WTl, 1024, 1024);
  k_gemm_m2<0,0><<<dim3(8,64), b256, 0, stream>>>(hsb, WTh, WTl, nullptr, pre, 8192, 1024, 1024);
  k_conv4<<<dim3(64,4,2), b256, 0, stream>>>(pre, cvw, vvb, 0);
  // beta (reads hs f32)
  k_beta<<<dim3(2048), b256, 0, stream>>>(hs, Wb, beta);
  // delta rule (overwrites uFb/wFb — WT dead)
  k_pre2<<<dim3(128,8), b256, 0, stream>>>(qn, kn, vvb, beta, uFb, wFb, aFb, aFl, kTb);
  k_scan5<<<dim3(16), dim3(512), 0, stream>>>(qn, wFb, uFb, kTb, aFb, aFl, dlt);
  // fuse + output projection (f32 out); WT(Wo) in uFb-space (dead after scan)
  k_fuse<<<dim3(64,4,2), b256, 0, stream>>>(vvb, dlt, fw, fsw, flw, rmsw, fusedb);
  k_wT<<<dim3(32,32), b256, 0, stream>>>(Wo, WTh, WTl, 1024, 1024);
  k_gemm_m2<0,1><<<dim3(8,64), b256, 0, stream>>>(fusedb, WTh, WTl, nullptr, outb, 8192, 1024, 1024);

  (void)in_sizes; (void)n_in; (void)out_size; (void)ws_size;
}

// Round 9
// 3634.045 us; speedup vs baseline: 1.0006x; 1.0006x over previous
//
#include <hip/hip_runtime.h>
#include <cstdint>

typedef __bf16 bf16;
typedef __bf16 bf16x8 __attribute__((ext_vector_type(8)));
typedef __bf16 bf16x4 __attribute__((ext_vector_type(4)));
typedef short  s16x8  __attribute__((ext_vector_type(8)));
typedef float  f32x4  __attribute__((ext_vector_type(4)));

#define DEV __device__ __forceinline__

static const int LL = 4096, HH = 1024, NCH = 128;

DEV float b2f(bf16 x){ return (float)x; }
DEV bf16  f2b(float x){ return (bf16)x; }
DEV f32x4 mfma16(s16x8 a, s16x8 b, f32x4 c){
  return __builtin_amdgcn_mfma_f32_16x16x32_bf16(a, b, c, 0, 0, 0);
}
DEV s16x8 ldg8(const bf16* p){ return *(const s16x8*)p; }

// async global->LDS, 16B per lane (CK idiom: int->as(3)/as(1) via uintptr_t, no addrspacecast)
DEV void gld16(const bf16* g, bf16* l){
  auto* lp = reinterpret_cast<__attribute__((address_space(3))) uint32_t*>(
      reinterpret_cast<uintptr_t>(l));
  auto* gp = reinterpret_cast<const __attribute__((address_space(1))) uint32_t*>(
      reinterpret_cast<uintptr_t>(g));
  __builtin_amdgcn_global_load_lds(gp, lp, 16, 0, 0);
}

// single-wave LDS handoff: lgkmcnt drain + scheduling fence (rule #18).
// NOT __syncthreads(): hipcc prepends s_waitcnt vmcnt(0) to s_barrier, which would
// drain the cross-chunk global prefetch (R2 post-mortem: 22.5K cyc/chunk of exposed latency).
#define LDS_FENCE() do { asm volatile("s_waitcnt lgkmcnt(0)" ::: "memory"); \
                         __builtin_amdgcn_sched_barrier(0); } while(0)

// ---------------- hs f32 -> bf16 (once; all GEMM A-reads become bf16) ----------------
__global__ __launch_bounds__(256) void k_h2b(const float* __restrict__ X, bf16* __restrict__ Y){
  size_t i = ((size_t)blockIdx.x*256 + threadIdx.x)*8;
  float4 a = *(const float4*)(X+i), b = *(const float4*)(X+i+4);
  bf16x8 v;
  v[0]=f2b(a.x); v[1]=f2b(a.y); v[2]=f2b(a.z); v[3]=f2b(a.w);
  v[4]=f2b(b.x); v[5]=f2b(b.y); v[6]=f2b(b.z); v[7]=f2b(b.w);
  *(bf16x8*)(Y+i) = v;
}

// ---------------- weight transpose: W[K][N] f32 -> WT[N][K] bf16 hi + lo ----------------
__global__ __launch_bounds__(256) void k_wT(const float* __restrict__ W, bf16* __restrict__ Th,
                                            bf16* __restrict__ Tl, int K, int N){
  __shared__ float Ts[32][33];
  int t = threadIdx.x;
  int ni = blockIdx.x*32, ki = blockIdx.y*32;
  int r = t>>3, c4 = (t&7)*4;
  float4 v = *(const float4*)(W + (size_t)(ki+r)*N + ni + c4);
  Ts[r][c4+0]=v.x; Ts[r][c4+1]=v.y; Ts[r][c4+2]=v.z; Ts[r][c4+3]=v.w;
  __syncthreads();
  bf16x4 hh, llo;
  #pragma unroll
  for(int i=0;i<4;i++){
    float x = Ts[c4+i][r];
    bf16 hb = f2b(x); hh[i]=hb; llo[i]=f2b(x-(float)hb);
  }
  *(bf16x4*)(Th + (size_t)(ni+r)*K + ki + c4) = hh;
  *(bf16x4*)(Tl + (size_t)(ni+r)*K + ki + c4) = llo;
}

// ---------------- MFMA GEMM v2: A bf16 [M][K]; B as BT[N][K] bf16 hi/lo ----------------
// Double-buffered LDS staged by global_load_lds(16B): 1 barrier per K-step (its implicit
// vmcnt(0) drains the *next* tile's stage, issued before this step's compute -> overlap).
// Swizzle (rule #21): LDS dest linear (gload_lds requirement), global SOURCE column
// pre-XOR'd, read XOR'd: slot(row,cb') holds global colblk cb'^(row&3); reader of g uses
// cb'=g^(row&3) -> fetches g. XOR is an involution within the 64B row => bijective.
template<int EPI, int OF32>
__global__ __launch_bounds__(256) void k_gemm_m2(const bf16* __restrict__ A,
    const bf16* __restrict__ BTh, const bf16* __restrict__ BTl,
    const float* __restrict__ bias, void* __restrict__ Cp, int M, int N, int K){
  __shared__ __align__(16) bf16 As [2][128*32];
  __shared__ __align__(16) bf16 Bsh[2][128*32];
  __shared__ __align__(16) bf16 Bsl[2][128*32];
  int t = threadIdx.x;
  int w = t>>6, ln = t&63, lr = ln&15, lk = ln>>4;
  int wr = w>>1, wc = w&1;
  int m0 = blockIdx.y*128, n0 = blockIdx.x*128;
  f32x4 acc[4][4];
  #pragma unroll
  for(int m=0;m<4;m++)
    #pragma unroll
    for(int n=0;n<4;n++) acc[m][n] = f32x4{0.f,0.f,0.f,0.f};
  // stage geometry: per wave 2 instrs/array, instr j covers rows w*32+j*16 .. +15
  int srow[2], gcb[2];
  #pragma unroll
  for(int j=0;j<2;j++){
    srow[j] = w*32 + j*16 + (ln>>2);
    gcb[j]  = (ln&3) ^ (srow[j]&3);        // pre-swizzled source column block
  }
  auto STAGE = [&](int buf, int k0){
    #pragma unroll
    for(int j=0;j<2;j++){
      bf16* lb = &As[buf][(w*32+j*16)*32];  // wave-uniform base; HW adds lane*16
      gld16(A   + (size_t)(m0+srow[j])*K + k0 + gcb[j]*8, lb);
      lb = &Bsh[buf][(w*32+j*16)*32];
      gld16(BTh + (size_t)(n0+srow[j])*K + k0 + gcb[j]*8, lb);
      lb = &Bsl[buf][(w*32+j*16)*32];
      gld16(BTl + (size_t)(n0+srow[j])*K + k0 + gcb[j]*8, lb);
    }
  };
  STAGE(0, 0);
  __syncthreads();
  int cur = 0;
  for(int k0=0;k0<K;k0+=32){
    if(k0+32<K) STAGE(cur^1, k0+32);
    s16x8 a[4], bh[4], bl[4];
    #pragma unroll
    for(int m=0;m<4;m++){
      int row = wr*64 + m*16 + lr;
      a[m] = *(const s16x8*)((char*)As[cur] + row*64 + ((lk*16) ^ ((lr&3)<<4)));
    }
    #pragma unroll
    for(int n=0;n<4;n++){
      int row = wc*64 + n*16 + lr;
      int off = row*64 + ((lk*16) ^ ((lr&3)<<4));
      bh[n] = *(const s16x8*)((char*)Bsh[cur] + off);
      bl[n] = *(const s16x8*)((char*)Bsl[cur] + off);
    }
    #pragma unroll
    for(int m=0;m<4;m++)
      #pragma unroll
      for(int n=0;n<4;n++){
        acc[m][n] = mfma16(a[m], bh[n], acc[m][n]);
        acc[m][n] = mfma16(a[m], bl[n], acc[m][n]);
      }
    __syncthreads();   // drains vmcnt(0): next buffer fully staged; reads of cur done
    cur ^= 1;
  }
  #pragma unroll
  for(int m=0;m<4;m++)
    #pragma unroll
    for(int n=0;n<4;n++)
      #pragma unroll
      for(int r=0;r<4;r++){
        int gm = m0 + wr*64 + m*16 + lk*4 + r;
        int gn = n0 + wc*64 + n*16 + lr;
        float v = acc[m][n][r];
        if(EPI==1){ v += bias[gn]; v = 0.5f*v*(1.f + erff(v*0.70710678118f)); }
        if(OF32) ((float*)Cp)[(size_t)gm*N + gn] = v;
        else     ((bf16*)Cp)[(size_t)gm*N + gn] = f2b(v);
      }
}

// ---------------- beta = sigmoid(hs @ Wb), hs f32 ----------------
__global__ __launch_bounds__(256) void k_beta(const float* __restrict__ X, const float* __restrict__ Wb,
                                              float* __restrict__ beta){
  int row = blockIdx.x*4 + (threadIdx.x>>6), lane = threadIdx.x&63;
  const float* xp = X + (size_t)row*HH;
  float a0=0,a1=0,a2=0,a3=0;
  for(int k=lane;k<HH;k+=64){
    float x = xp[k];
    float4 wr = *(const float4*)(Wb + (size_t)k*4);
    a0 += x*wr.x; a1 += x*wr.y; a2 += x*wr.z; a3 += x*wr.w;
  }
  #pragma unroll
  for(int off=32;off>=1;off>>=1){
    a0 += __shfl_down(a0,off,64); a1 += __shfl_down(a1,off,64);
    a2 += __shfl_down(a2,off,64); a3 += __shfl_down(a3,off,64);
  }
  if(lane==0){
    beta[(size_t)row*4+0] = 1.f/(1.f+__expf(-a0));
    beta[(size_t)row*4+1] = 1.f/(1.f+__expf(-a1));
    beta[(size_t)row*4+2] = 1.f/(1.f+__expf(-a2));
    beta[(size_t)row*4+3] = 1.f/(1.f+__expf(-a3));
  }
}

// ---------------- depthwise causal conv K=4 + silu (+ per-head l2norm) ----------------
__global__ __launch_bounds__(256) void k_conv4(const bf16* __restrict__ pre, const float* __restrict__ filt,
                                               bf16* __restrict__ outp, int do_norm){
  __shared__ float red[4][8];
  int tx = threadIdx.x, head = blockIdx.y, b = blockIdx.z; int l0 = blockIdx.x*64;
  int wv = tx>>6, lane = tx&63;
  int c = head*256 + tx;
  const bf16* p = pre + (size_t)b*LL*HH + c;
  const float* fp = filt + (size_t)c*4;
  float f0=fp[0], f1=fp[1], f2=fp[2], f3=fp[3];
  float x0,x1,x2;
  if(l0>0){ x0=b2f(p[(size_t)(l0-3)*HH]); x1=b2f(p[(size_t)(l0-2)*HH]); x2=b2f(p[(size_t)(l0-1)*HH]); }
  else { x0=x1=x2=0.f; }
  for(int g=0; g<8; g++){
    float y[8];
    #pragma unroll
    for(int i=0;i<8;i++){
      int l = l0+g*8+i;
      float x3 = b2f(p[(size_t)l*HH]);
      float u = f0*x0 + f1*x1 + f2*x2 + f3*x3;
      x0=x1; x1=x2; x2=x3;
      y[i] = u/(1.f+__expf(-u));
    }
    if(do_norm){
      float sq[8];
      #pragma unroll
      for(int i=0;i<8;i++) sq[i]=y[i]*y[i];
      #pragma unroll
      for(int off=32;off>=1;off>>=1)
        #pragma unroll
        for(int i=0;i<8;i++) sq[i] += __shfl_down(sq[i],off,64);
      if(lane==0){
        #pragma unroll
        for(int i=0;i<8;i++) red[wv][i]=sq[i];
      }
      __syncthreads();
      float tot[8];
      #pragma unroll
      for(int i=0;i<8;i++) tot[i]=red[0][i]+red[1][i]+red[2][i]+red[3][i];
      __syncthreads();
      #pragma unroll
      for(int i=0;i<8;i++) y[i] *= rsqrtf(tot[i]);
    }
    #pragma unroll
    for(int i=0;i<8;i++) outp[(size_t)(b*LL + l0+g*8+i)*HH + c] = f2b(y[i]);
  }
}

// ---------------- gate: softmax4(h1 @ Wf2 + bf2), Wf2 f32 [2048][16] ----------------
__global__ __launch_bounds__(256) void k_gate(const bf16* __restrict__ h1, const float* __restrict__ W2,
                                              const float* __restrict__ bf2v, float* __restrict__ fw){
  int row = blockIdx.x*4 + (threadIdx.x>>6), lane = threadIdx.x&63;
  const bf16* hp = h1 + (size_t)row*2048;
  float acc[16];
  #pragma unroll
  for(int c=0;c<16;c++) acc[c]=0.f;
  for(int k=lane;k<2048;k+=64){
    float x = b2f(hp[k]);
    const float* wr = W2 + (size_t)k*16;
    float4 w0 = *(const float4*)(wr), w1 = *(const float4*)(wr+4);
    float4 w2 = *(const float4*)(wr+8), w3 = *(const float4*)(wr+12);
    acc[0]+=x*w0.x; acc[1]+=x*w0.y; acc[2]+=x*w0.z; acc[3]+=x*w0.w;
    acc[4]+=x*w1.x; acc[5]+=x*w1.y; acc[6]+=x*w1.z; acc[7]+=x*w1.w;
    acc[8]+=x*w2.x; acc[9]+=x*w2.y; acc[10]+=x*w2.z; acc[11]+=x*w2.w;
    acc[12]+=x*w3.x; acc[13]+=x*w3.y; acc[14]+=x*w3.z; acc[15]+=x*w3.w;
  }
  #pragma unroll
  for(int off=32;off>=1;off>>=1)
    #pragma unroll
    for(int c=0;c<16;c++) acc[c] += __shfl_down(acc[c],off,64);
  if(lane==0){
    #pragma unroll
    for(int h=0;h<4;h++){
      float s0=acc[h*4+0]+bf2v[h*4+0], s1=acc[h*4+1]+bf2v[h*4+1];
      float s2=acc[h*4+2]+bf2v[h*4+2], s3=acc[h*4+3]+bf2v[h*4+3];
      float mx = fmaxf(fmaxf(s0,s1),fmaxf(s2,s3));
      float e0=__expf(s0-mx), e1=__expf(s1-mx), e2=__expf(s2-mx), e3=__expf(s3-mx);
      float inv = 1.f/(e0+e1+e2+e3);
      fw[(size_t)row*16+h*4+0]=e0*inv; fw[(size_t)row*16+h*4+1]=e1*inv;
      fw[(size_t)row*16+h*4+2]=e2*inv; fw[(size_t)row*16+h*4+3]=e3*inv;
    }
  }
}

// ---------------- per-chunk precompute (VALU): T, u, w, attn(bf16 hi/lo), kT ----------------
__global__ __launch_bounds__(256) void k_pre2(const bf16* __restrict__ qn, const bf16* __restrict__ kn,
    const bf16* __restrict__ vv, const float* __restrict__ beta,
    bf16* __restrict__ uFb, bf16* __restrict__ wFb, bf16* __restrict__ aFb, bf16* __restrict__ aFl,
    bf16* __restrict__ kTb){
  __shared__ __align__(16) bf16 qs[8192], ks[8192], vs[8192];
  __shared__ float T[32][33];
  __shared__ float bet[32];
  int ch = blockIdx.x, bh = blockIdx.y, b = bh>>2, h = bh&3;
  int t = threadIdx.x;
  int l0 = ch*32;
  size_t rowbase = ((size_t)(b*LL+l0))*HH + h*256;
  #pragma unroll
  for(int i=0;i<4;i++){
    int f = i*256+t, row = f>>5, sub = f&31;
    size_t go = rowbase + (size_t)row*HH + sub*8;
    *(bf16x8*)&qs[f*8] = *(const bf16x8*)(qn+go);
    *(bf16x8*)&ks[f*8] = *(const bf16x8*)(kn+go);
    *(bf16x8*)&vs[f*8] = *(const bf16x8*)(vv+go);
  }
  if(t<32) bet[t] = beta[(size_t)(b*LL+l0+t)*4 + h];
  __syncthreads();
  int c = t>>3, e0 = (t&7)*4;
  float d0=0,d1=0,d2=0,d3=0, a0=0,a1=0,a2=0,a3=0;
  for(int d=0; d<256; d++){
    float kc = b2f(ks[c*256+d]);
    float qc = b2f(qs[c*256+d]);
    float k0 = b2f(ks[(e0+0)*256+d]);
    float k1 = b2f(ks[(e0+1)*256+d]);
    float k2 = b2f(ks[(e0+2)*256+d]);
    float k3 = b2f(ks[(e0+3)*256+d]);
    d0 += kc*k0; d1 += kc*k1; d2 += kc*k2; d3 += kc*k3;
    a0 += qc*k0; a1 += qc*k1; a2 += qc*k2; a3 += qc*k3;
  }
  float bc = bet[c];
  T[c][e0+0] = (c>e0+0)? -bc*d0 : 0.f;
  T[c][e0+1] = (c>e0+1)? -bc*d1 : 0.f;
  T[c][e0+2] = (c>e0+2)? -bc*d2 : 0.f;
  T[c][e0+3] = (c>e0+3)? -bc*d3 : 0.f;
  size_t ab = ((size_t)(bh*NCH+ch))*1024;
  {
    float av[4] = { (c>=e0+0)? a0 : 0.f, (c>=e0+1)? a1 : 0.f,
                    (c>=e0+2)? a2 : 0.f, (c>=e0+3)? a3 : 0.f };
    #pragma unroll
    for(int i=0;i<4;i++){
      bf16 hb = f2b(av[i]);
      aFb[ab + c*32 + e0+i] = hb;
      aFl[ab + c*32 + e0+i] = f2b(av[i] - (float)hb);
    }
  }
  __syncthreads();
  // forward substitution — lanes 0..31 of wave 0, lockstep; volatile forces LDS traffic
  if(t < 32){
    volatile float (*Tv)[33] = (volatile float (*)[33])T;
    int j = t;
    for(int i=1;i<32;i++){
      float s2 = 0.f;
      for(int m=0;m<i;m++) s2 += Tv[i][m]*Tv[m][j];
      Tv[i][j] += s2;
    }
    Tv[j][j] += 1.f;
  }
  __syncthreads();
  int dv0 = (t&7)*32;
  float uacc[32], wacc[32];
  #pragma unroll
  for(int j=0;j<32;j++){ uacc[j]=0.f; wacc[j]=0.f; }
  for(int c2=0;c2<32;c2++){
    float coef = T[c][c2]*bet[c2];
    #pragma unroll
    for(int j=0;j<32;j++){
      uacc[j] += coef * b2f(vs[c2*256+dv0+j]);
      wacc[j] += coef * b2f(ks[c2*256+dv0+j]);
    }
  }
  size_t ub = ((size_t)(bh*NCH+ch))*8192 + (size_t)c*256 + dv0;
  #pragma unroll
  for(int j=0;j<32;j++){ uFb[ub+j] = f2b(uacc[j]); wFb[ub+j] = f2b(wacc[j]); }
  // kT emit: thread t owns dk=t, writes kT[dk][0..31] (A-operand layout for S-update MFMA)
  {
    bf16* kout = kTb + ((size_t)(bh*NCH+ch))*8192 + (size_t)t*32;
    #pragma unroll
    for(int q8=0;q8<4;q8++){
      bf16x8 v8;
      #pragma unroll
      for(int i=0;i<8;i++) v8[i] = ks[(q8*8+i)*256 + t];
      *(bf16x8*)(kout + q8*8) = v8;
    }
  }
}

// ---------------- MFMA chunkwise scan v5b: 8 waves/block, 2 waves/SIMD (TLP) ----------------
// R8 post-mortem: __launch_bounds__(512,2) acted as min-2-BLOCKS/CU (CUDA semantics) ->
// 4 waves/SIMD -> 128-VGPR cap -> ~100 regs spilled to scratch -> 8x regression
// (VGPR_Count=128, WRITE_SIZE +5MB of scratch). Fix: bare __launch_bounds__(512) — the
// only occupancy constraint is the block shape (8 waves / 4 SIMDs = 2 waves/SIMD), which
// caps VGPR at 256; the 224-VGPR body fits with zero spill. Body identical to k_scan4.
// Waves are fully independent (own S state, own LDS slice, no __syncthreads); all 8 waves
// read IDENTICAL w/kT/attn streams -> L1 reuse. LDS 147456 B static.
__global__ __launch_bounds__(512) void k_scan5(const bf16* __restrict__ qn,
    const bf16* __restrict__ wFb, const bf16* __restrict__ uFb,
    const bf16* __restrict__ kTb, const bf16* __restrict__ aFb, const bf16* __restrict__ aFl,
    bf16* __restrict__ delta){
  __shared__ __align__(16) char LDSall[8][18432];  // per wave: STh(8K) STl(8K) UTh(1K) UTl(1K)
  int tid = threadIdx.x;
  int wid = tid>>6, l = tid&63;
  char* STh = LDSall[wid];
  char* STl = STh + 8192;
  char* UTh = STh + 16384;
  char* UTl = STh + 17408;
  // blocks 0..15: bh = id&7 (blocks b and b+8 share bh and, round-robin, an XCD L2)
  int bh = blockIdx.x & 7, js = (blockIdx.x>>3)*8 + wid;
  int b = bh>>2, h = bh&3;
  int lr = l & 15, lk = l >> 4;
  int jb = js*16;
  float4 z4 = make_float4(0.f,0.f,0.f,0.f);
  #pragma unroll
  for(int i=0;i<8;i++){ ((float4*)STh)[l+i*64] = z4; ((float4*)STl)[l+i*64] = z4; }
  LDS_FENCE();
  f32x4 Sacc[16];
  #pragma unroll
  for(int i=0;i<16;i++) Sacc[i] = f32x4{0.f,0.f,0.f,0.f};
  const int Xst = (lr&7)<<4;   // ST row swizzle (bits 4-6 of FULL in-row byte offset, rule #21)
  const int Xut = (lr&3)<<4;   // UT row swizzle (bits 4-5)
  const bf16* wp  = wFb + (size_t)bh*NCH*8192;
  const bf16* up  = uFb + (size_t)bh*NCH*8192;
  const bf16* kp  = kTb + (size_t)bh*NCH*8192;
  const bf16* aph = aFb + (size_t)bh*NCH*1024;
  const bf16* apl = aFl + (size_t)bh*NCH*1024;
  const bf16* qp  = qn + (size_t)b*LL*HH + h*256;
  // prefetch registers (chunk 0)
  s16x8 Wr[16], Qr[16], Kr[16], A0h, A1h, A0l, A1l;
  bf16 Ur[8];
  #pragma unroll
  for(int t8=0;t8<8;t8++){
    Wr[t8]   = ldg8(wp + lr*256      + t8*32 + lk*8);
    Wr[8+t8] = ldg8(wp + (16+lr)*256 + t8*32 + lk*8);
    Qr[t8]   = ldg8(qp + (size_t)lr*HH      + t8*32 + lk*8);
    Qr[8+t8] = ldg8(qp + (size_t)(16+lr)*HH + t8*32 + lk*8);
  }
  #pragma unroll
  for(int dt=0;dt<16;dt++) Kr[dt] = ldg8(kp + (dt*16+lr)*32 + lk*8);
  A0h = ldg8(aph + lr*32 + lk*8); A1h = ldg8(aph + (16+lr)*32 + lk*8);
  A0l = ldg8(apl + lr*32 + lk*8); A1l = ldg8(apl + (16+lr)*32 + lk*8);
  #pragma unroll
  for(int r8=0;r8<8;r8++){
    int rr = (r8>>2)*16 + lk*4 + (r8&3);
    Ur[r8] = up[(size_t)rr*256 + jb + lr];
  }
  for(int ci=0; ci<NCH; ci++){
    size_t nxw = (ci<NCH-1)? 8192 : 0;            // next-chunk strides (clamped at tail)
    size_t nxa = (ci<NCH-1)? 1024 : 0;
    size_t nxq = (ci<NCH-1)? (size_t)32*HH : 0;
    // ---- Phase 1: ST fragments to regs, then the 64-MFMA block
    s16x8 sth[8], stl[8];
    #pragma unroll
    for(int t8=0;t8<8;t8++){
      int ro = lr*512 + ((t8*64 + lk*16) ^ Xst);
      sth[t8] = *(const s16x8*)(STh + ro);
      stl[t8] = *(const s16x8*)(STl + ro);
    }
    f32x4 wh0={0.f,0.f,0.f,0.f}, wl0=wh0, wh1=wh0, wl1=wh0;
    f32x4 qh0=wh0, ql0=wh0, qh1=wh0, ql1=wh0;
    #pragma unroll
    for(int t8=0;t8<8;t8++){
      wh0 = mfma16(Wr[t8],   sth[t8], wh0); wl0 = mfma16(Wr[t8],   stl[t8], wl0);
      wh1 = mfma16(Wr[8+t8], sth[t8], wh1); wl1 = mfma16(Wr[8+t8], stl[t8], wl1);
      qh0 = mfma16(Qr[t8],   sth[t8], qh0); ql0 = mfma16(Qr[t8],   stl[t8], ql0);
      qh1 = mfma16(Qr[8+t8], sth[t8], qh1); ql1 = mfma16(Qr[8+t8], stl[t8], ql1);
    }
    f32x4 ws0 = wh0+wl0, ws1 = wh1+wl1;
    f32x4 qs0 = qh0+ql0, qs1 = qh1+ql1;
    // prefetch next W,Q (regs fully consumed above)
    #pragma unroll
    for(int t8=0;t8<8;t8++){
      Wr[t8]   = ldg8(wp + nxw + lr*256      + t8*32 + lk*8);
      Wr[8+t8] = ldg8(wp + nxw + (16+lr)*256 + t8*32 + lk*8);
      Qr[t8]   = ldg8(qp + nxq + (size_t)lr*HH      + t8*32 + lk*8);
      Qr[8+t8] = ldg8(qp + nxq + (size_t)(16+lr)*HH + t8*32 + lk*8);
    }
    // ---- Phase 2: u_t = u - wS -> UT hi/lo (lane holds (c=ct*16+lk*4+r, j=lr))
    #pragma unroll
    for(int ct=0;ct<2;ct++){
      f32x4 w = ct? ws1 : ws0;
      bf16x4 hh, llo;
      #pragma unroll
      for(int r=0;r<4;r++){
        float v = b2f(Ur[ct*4+r]) - w[r];
        bf16 hb = f2b(v); hh[r]=hb; llo[r]=f2b(v-(float)hb);
      }
      int utw = lr*64 + ((ct*32 + lk*8) ^ Xut);
      *(bf16x4*)(UTh+utw)=hh; *(bf16x4*)(UTl+utw)=llo;
    }
    #pragma unroll
    for(int r8=0;r8<8;r8++){
      int rr = (r8>>2)*16 + lk*4 + (r8&3);
      Ur[r8] = up[nxw + (size_t)rr*256 + jb + lr];
    }
    LDS_FENCE();   // cross-lane UT handoff (wave-local lgkmcnt; no barrier)
    int utR = lr*64 + ((lk*16) ^ Xut);
    s16x8 th = *(const s16x8*)(UTh + utR);
    s16x8 tl = *(const s16x8*)(UTl + utR);
    // ---- Phase 3: o = qS + attn@u_t
    qs0 = mfma16(A0h, th, qs0); qs0 = mfma16(A0h, tl, qs0); qs0 = mfma16(A0l, th, qs0);
    qs1 = mfma16(A1h, th, qs1); qs1 = mfma16(A1h, tl, qs1); qs1 = mfma16(A1l, th, qs1);
    bf16* dp = delta + ((size_t)(b*LL + ci*32))*HH + h*256 + jb + lr;
    #pragma unroll
    for(int ct=0;ct<2;ct++){
      f32x4 o = ct? qs1 : qs0;
      #pragma unroll
      for(int r=0;r<4;r++) dp[(size_t)(ct*16 + lk*4 + r)*HH] = f2b(o[r]);
    }
    A0h = ldg8(aph + nxa + lr*32 + lk*8); A1h = ldg8(aph + nxa + (16+lr)*32 + lk*8);
    A0l = ldg8(apl + nxa + lr*32 + lk*8); A1l = ldg8(apl + nxa + (16+lr)*32 + lk*8);
    // ---- Phase 4: S[dk][j] += k^T @ u_t
    #pragma unroll
    for(int dt=0;dt<16;dt++){
      Sacc[dt] = mfma16(Kr[dt], th, Sacc[dt]);
      Sacc[dt] = mfma16(Kr[dt], tl, Sacc[dt]);
    }
    #pragma unroll
    for(int dt=0;dt<16;dt++) Kr[dt] = ldg8(kp + nxw + (size_t)(dt*16+lr)*32 + lk*8);
    // ---- Phase 5: restage S -> LDS bf16 hi/lo
    #pragma unroll
    for(int dt=0;dt<16;dt++){
      bf16x4 hh, llo;
      #pragma unroll
      for(int r=0;r<4;r++){
        float v = Sacc[dt][r];
        bf16 hb=f2b(v); hh[r]=hb; llo[r]=f2b(v-(float)hb);
      }
      int stw = lr*512 + ((dt*32 + lk*8) ^ Xst);
      *(bf16x4*)(STh+stw)=hh; *(bf16x4*)(STl+stw)=llo;
    }
    LDS_FENCE();   // S restage visible before next chunk's phase-1 reads
    wp += nxw; up += nxw; kp += nxw; aph += nxa; apl += nxa; qp += nxq;
  }
}

// ---------------- FIR convs + gated fusion + RMSNorm ----------------
__global__ __launch_bounds__(256) void k_fuse(const bf16* __restrict__ vv, const bf16* __restrict__ delta,
    const float* __restrict__ fw, const float* __restrict__ fsw, const float* __restrict__ flw,
    const float* __restrict__ rmsw, bf16* __restrict__ fused){
  __shared__ float red[4][8];
  int tx = threadIdx.x, head = blockIdx.y, b = blockIdx.z; int l0 = blockIdx.x*64;
  int wv = tx>>6, lane = tx&63;
  int c = head*256 + tx;
  const bf16* vp = vv + (size_t)b*LL*HH + c;
  float fs[7], fl[64];
  #pragma unroll
  for(int j=0;j<7;j++) fs[j] = fsw[(size_t)c*7+j];
  #pragma unroll
  for(int j=0;j<64;j++) fl[j] = flw[(size_t)c*64+j];
  float win[64];
  #pragma unroll
  for(int i=0;i<63;i++){ int l=l0-63+i; win[i] = (l>=0)? b2f(vp[(size_t)l*HH]) : 0.f; }
  float rw = rmsw[tx];
  for(int g=0; g<8; g++){
    float oo[8], sq[8];
    #pragma unroll
    for(int i=0;i<8;i++){
      int s = g*8+i; int l = l0+s;
      win[(s+63)&63] = b2f(vp[(size_t)l*HH]);
      float ll2 = 0.f;
      #pragma unroll
      for(int tp=0;tp<64;tp++) ll2 += fl[tp]*win[(s+tp)&63];
      float ls = 0.f;
      #pragma unroll
      for(int tp=0;tp<7;tp++) ls += fs[tp]*win[(s+57+tp)&63];
      float dl = b2f(delta[(size_t)(b*LL+l)*HH + c]);
      float vh = win[(s+63)&63];
      const float* fp = fw + (size_t)(b*LL+l)*16 + head*4;
      float o = fp[0]*ls + fp[1]*ll2 + fp[2]*dl + fp[3]*vh;
      oo[i]=o; sq[i]=o*o;
    }
    #pragma unroll
    for(int off=32;off>=1;off>>=1)
      #pragma unroll
      for(int i=0;i<8;i++) sq[i] += __shfl_down(sq[i],off,64);
    if(lane==0){
      #pragma unroll
      for(int i=0;i<8;i++) red[wv][i]=sq[i];
    }
    __syncthreads();
    float tot[8];
    #pragma unroll
    for(int i=0;i<8;i++) tot[i]=red[0][i]+red[1][i]+red[2][i]+red[3][i];
    __syncthreads();
    #pragma unroll
    for(int i=0;i<8;i++){
      int l = l0+g*8+i;
      fused[(size_t)(b*LL+l)*HH + c] = f2b(oo[i]*rsqrtf(tot[i]*(1.f/256.f)+1e-5f)*rw);
    }
  }
}

extern "C" void kernel_launch(void* const* d_in, const int* in_sizes, int n_in,
                              void* d_out, int out_size, void* d_ws, size_t ws_size,
                              hipStream_t stream){
  const float* hs  =(const float*)d_in[0];
  const float* Wq  =(const float*)d_in[1];
  const float* Wk  =(const float*)d_in[2];
  const float* Wv  =(const float*)d_in[3];
  const float* Wb  =(const float*)d_in[4];
  const float* cqw =(const float*)d_in[5];
  const float* ckw =(const float*)d_in[6];
  const float* cvw =(const float*)d_in[7];
  const float* fsw =(const float*)d_in[8];
  const float* flw =(const float*)d_in[9];
  const float* Wf1 =(const float*)d_in[10];
  const float* bf1 =(const float*)d_in[11];
  const float* Wf2 =(const float*)d_in[12];
  const float* bf2v=(const float*)d_in[13];
  const float* rmsw=(const float*)d_in[14];
  const float* Wo  =(const float*)d_in[15];

  char* ws = (char*)d_ws;
  size_t off = 0;
  auto alloc = [&](size_t bytes)->char*{
    char* p = ws + off; off = (off + bytes + 255) & ~(size_t)255; return p;
  };
  bf16* pre   = (bf16*)alloc(8192ull*1024*2);   // q/k/v pre-conv (sequential); later kTb; later fusedb
  bf16* qn    = (bf16*)alloc(8192ull*1024*2);
  bf16* kn    = (bf16*)alloc(8192ull*1024*2);
  bf16* vvb   = (bf16*)alloc(8192ull*1024*2);
  float* beta = (float*)alloc(8192ull*4*4);
  bf16* uFb   = (bf16*)alloc(8ull*128*8192*2);  // h1 aliases uFb+wFb (32MB) before k_pre2
  bf16* wFb   = (bf16*)alloc(8ull*128*8192*2);
  bf16* aFb   = (bf16*)alloc(8ull*128*1024*4);  // hi (2MB) + lo (2MB) attn, bf16
  float* fw   = (float*)alloc(8192ull*16*4);
  bf16* aFl   = aFb + 8ull*128*1024;
  bf16* h1    = uFb;                            // dead once fw extracted
  bf16* kTb   = pre;                            // pre dead after conv-v; dead again before k_fuse
  bf16* dlt   = (bf16*)d_out;                   // first 16MB of the 32MB f32 out; dead before final GEMM
  bf16* fusedb= pre;
  float* outb = (float*)d_out;
  // aliased staging (no extra workspace):
  //  - hsb (bf16 hs, 16MB): vvb-space — vvb is only written by conv-v, the LAST hs consumer ran
  //  - WT(Wf1) 8MB: qn-space (qn written by conv-q, after the gate GEMM)
  //  - WT(Wq/Wk/Wv/Wo) 4MB: uFb-space (dead between k_gate and k_pre2, and after k_scan5)
  bf16* hsb  = vvb;
  bf16* WT1h = qn;            bf16* WT1l = qn + 2048ull*1024;
  bf16* WTh  = uFb;           bf16* WTl  = uFb + 1024ull*1024;

  dim3 b256(256);
  // hs -> bf16 once
  k_h2b<<<dim3(4096), b256, 0, stream>>>(hs, hsb);
  // gate path FIRST (h1 aliases uFb/wFb; WT(Wf1) lives in qn-space)
  k_wT<<<dim3(64,32), b256, 0, stream>>>(Wf1, WT1h, WT1l, 1024, 2048);
  k_gemm_m2<1,0><<<dim3(16,64), b256, 0, stream>>>(hsb, WT1h, WT1l, bf1, h1, 8192, 2048, 1024);
  k_gate<<<dim3(2048), b256, 0, stream>>>(h1, Wf2, bf2v, fw);
  // q path (WT in uFb-space, dead until k_pre2)
  k_wT<<<dim3(32,32), b256, 0, stream>>>(Wq, WTh, WTl, 1024, 1024);
  k_gemm_m2<0,0><<<dim3(8,64), b256, 0, stream>>>(hsb, WTh, WTl, nullptr, pre, 8192, 1024, 1024);
  k_conv4<<<dim3(64,4,2), b256, 0, stream>>>(pre, cqw, qn, 1);
  // k path
  k_wT<<<dim3(32,32), b256, 0, stream>>>(Wk, WTh, WTl, 1024, 1024);
  k_gemm_m2<0,0><<<dim3(8,64), b256, 0, stream>>>(hsb, WTh, WTl, nullptr, pre, 8192, 1024, 1024);
  k_conv4<<<dim3(64,4,2), b256, 0, stream>>>(pre, ckw, kn, 1);
  // v path (last hsb use, then conv-v overwrites hsb with vvb)
  k_wT<<<dim3(32,32), b256, 0, stream>>>(Wv, WTh, WTl, 1024, 1024);
  k_gemm_m2<0,0><<<dim3(8,64), b256, 0, stream>>>(hsb, WTh, WTl, nullptr, pre, 8192, 1024, 1024);
  k_conv4<<<dim3(64,4,2), b256, 0, stream>>>(pre, cvw, vvb, 0);
  // beta (reads hs f32)
  k_beta<<<dim3(2048), b256, 0, stream>>>(hs, Wb, beta);
  // delta rule (overwrites uFb/wFb — WT dead)
  k_pre2<<<dim3(128,8), b256, 0, stream>>>(qn, kn, vvb, beta, uFb, wFb, aFb, aFl, kTb);
  k_scan5<<<dim3(16), dim3(512), 0, stream>>>(qn, wFb, uFb, kTb, aFb, aFl, dlt);
  // fuse + output projection (f32 out); WT(Wo) in uFb-space (dead after scan)
  k_fuse<<<dim3(64,4,2), b256, 0, stream>>>(vvb, dlt, fw, fsw, flw, rmsw, fusedb);
  k_wT<<<dim3(32,32), b256, 0, stream>>>(Wo, WTh, WTl, 1024, 1024);
  k_gemm_m2<0,1><<<dim3(8,64), b256, 0, stream>>>(fusedb, WTh, WTl, nullptr, outb, 8192, 1024, 1024);

  (void)in_sizes; (void)n_in; (void)out_size; (void)ws_size;
}

// Round 11
// 1235.685 us; speedup vs baseline: 2.9427x; 2.9409x over previous
//
#include <hip/hip_runtime.h>
#include <cstdint>

typedef __bf16 bf16;
typedef __bf16 bf16x8 __attribute__((ext_vector_type(8)));
typedef __bf16 bf16x4 __attribute__((ext_vector_type(4)));
typedef short  s16x8  __attribute__((ext_vector_type(8)));
typedef float  f32x4  __attribute__((ext_vector_type(4)));

#define DEV __device__ __forceinline__

static const int LL = 4096, HH = 1024, NCH = 128;

DEV float b2f(bf16 x){ return (float)x; }
DEV bf16  f2b(float x){ return (bf16)x; }
DEV f32x4 mfma16(s16x8 a, s16x8 b, f32x4 c){
  return __builtin_amdgcn_mfma_f32_16x16x32_bf16(a, b, c, 0, 0, 0);
}
DEV s16x8 ldg8(const bf16* p){ return *(const s16x8*)p; }

// async global->LDS, 16B per lane (CK idiom: int->as(3)/as(1) via uintptr_t, no addrspacecast)
DEV void gld16(const bf16* g, bf16* l){
  auto* lp = reinterpret_cast<__attribute__((address_space(3))) uint32_t*>(
      reinterpret_cast<uintptr_t>(l));
  auto* gp = reinterpret_cast<const __attribute__((address_space(1))) uint32_t*>(
      reinterpret_cast<uintptr_t>(g));
  __builtin_amdgcn_global_load_lds(gp, lp, 16, 0, 0);
}

// single-wave LDS handoff: lgkmcnt drain with "memory" clobber.
// R10: sched_barrier(0) REMOVED — rule #18's hazard applies to inline-asm ds_read
// (opaque dataflow); our LDS accesses are IR loads/stores which cannot cross the
// asm memory clobber, and consuming MFMAs are data-dependent on them. The barrier
// was a total scheduling wall 2x/chunk (6040 cyc/chunk vs ~1500 issue cycles).
// NOT __syncthreads(): hipcc prepends s_waitcnt vmcnt(0) to s_barrier, which would
// drain the cross-chunk global prefetch (R2 post-mortem).
#define LDS_WAIT() asm volatile("s_waitcnt lgkmcnt(0)" ::: "memory")

// ---------------- hs f32 -> bf16 (once; all GEMM A-reads become bf16) ----------------
__global__ __launch_bounds__(256) void k_h2b(const float* __restrict__ X, bf16* __restrict__ Y){
  size_t i = ((size_t)blockIdx.x*256 + threadIdx.x)*8;
  float4 a = *(const float4*)(X+i), b = *(const float4*)(X+i+4);
  bf16x8 v;
  v[0]=f2b(a.x); v[1]=f2b(a.y); v[2]=f2b(a.z); v[3]=f2b(a.w);
  v[4]=f2b(b.x); v[5]=f2b(b.y); v[6]=f2b(b.z); v[7]=f2b(b.w);
  *(bf16x8*)(Y+i) = v;
}

// ---------------- weight transpose: W[K][N] f32 -> WT[N][K] bf16 hi + lo ----------------
__global__ __launch_bounds__(256) void k_wT(const float* __restrict__ W, bf16* __restrict__ Th,
                                            bf16* __restrict__ Tl, int K, int N){
  __shared__ float Ts[32][33];
  int t = threadIdx.x;
  int ni = blockIdx.x*32, ki = blockIdx.y*32;
  int r = t>>3, c4 = (t&7)*4;
  float4 v = *(const float4*)(W + (size_t)(ki+r)*N + ni + c4);
  Ts[r][c4+0]=v.x; Ts[r][c4+1]=v.y; Ts[r][c4+2]=v.z; Ts[r][c4+3]=v.w;
  __syncthreads();
  bf16x4 hh, llo;
  #pragma unroll
  for(int i=0;i<4;i++){
    float x = Ts[c4+i][r];
    bf16 hb = f2b(x); hh[i]=hb; llo[i]=f2b(x-(float)hb);
  }
  *(bf16x4*)(Th + (size_t)(ni+r)*K + ki + c4) = hh;
  *(bf16x4*)(Tl + (size_t)(ni+r)*K + ki + c4) = llo;
}

// ---------------- MFMA GEMM v2: A bf16 [M][K]; B as BT[N][K] bf16 hi/lo ----------------
// Double-buffered LDS staged by global_load_lds(16B): 1 barrier per K-step (its implicit
// vmcnt(0) drains the *next* tile's stage, issued before this step's compute -> overlap).
// Swizzle (rule #21): LDS dest linear (gload_lds requirement), global SOURCE column
// pre-XOR'd, read XOR'd: slot(row,cb') holds global colblk cb'^(row&3); reader of g uses
// cb'=g^(row&3) -> fetches g. XOR is an involution within the 64B row => bijective.
template<int EPI, int OF32>
__global__ __launch_bounds__(256) void k_gemm_m2(const bf16* __restrict__ A,
    const bf16* __restrict__ BTh, const bf16* __restrict__ BTl,
    const float* __restrict__ bias, void* __restrict__ Cp, int M, int N, int K){
  __shared__ __align__(16) bf16 As [2][128*32];
  __shared__ __align__(16) bf16 Bsh[2][128*32];
  __shared__ __align__(16) bf16 Bsl[2][128*32];
  int t = threadIdx.x;
  int w = t>>6, ln = t&63, lr = ln&15, lk = ln>>4;
  int wr = w>>1, wc = w&1;
  int m0 = blockIdx.y*128, n0 = blockIdx.x*128;
  f32x4 acc[4][4];
  #pragma unroll
  for(int m=0;m<4;m++)
    #pragma unroll
    for(int n=0;n<4;n++) acc[m][n] = f32x4{0.f,0.f,0.f,0.f};
  // stage geometry: per wave 2 instrs/array, instr j covers rows w*32+j*16 .. +15
  int srow[2], gcb[2];
  #pragma unroll
  for(int j=0;j<2;j++){
    srow[j] = w*32 + j*16 + (ln>>2);
    gcb[j]  = (ln&3) ^ (srow[j]&3);        // pre-swizzled source column block
  }
  auto STAGE = [&](int buf, int k0){
    #pragma unroll
    for(int j=0;j<2;j++){
      bf16* lb = &As[buf][(w*32+j*16)*32];  // wave-uniform base; HW adds lane*16
      gld16(A   + (size_t)(m0+srow[j])*K + k0 + gcb[j]*8, lb);
      lb = &Bsh[buf][(w*32+j*16)*32];
      gld16(BTh + (size_t)(n0+srow[j])*K + k0 + gcb[j]*8, lb);
      lb = &Bsl[buf][(w*32+j*16)*32];
      gld16(BTl + (size_t)(n0+srow[j])*K + k0 + gcb[j]*8, lb);
    }
  };
  STAGE(0, 0);
  __syncthreads();
  int cur = 0;
  for(int k0=0;k0<K;k0+=32){
    if(k0+32<K) STAGE(cur^1, k0+32);
    s16x8 a[4], bh[4], bl[4];
    #pragma unroll
    for(int m=0;m<4;m++){
      int row = wr*64 + m*16 + lr;
      a[m] = *(const s16x8*)((char*)As[cur] + row*64 + ((lk*16) ^ ((lr&3)<<4)));
    }
    #pragma unroll
    for(int n=0;n<4;n++){
      int row = wc*64 + n*16 + lr;
      int off = row*64 + ((lk*16) ^ ((lr&3)<<4));
      bh[n] = *(const s16x8*)((char*)Bsh[cur] + off);
      bl[n] = *(const s16x8*)((char*)Bsl[cur] + off);
    }
    #pragma unroll
    for(int m=0;m<4;m++)
      #pragma unroll
      for(int n=0;n<4;n++){
        acc[m][n] = mfma16(a[m], bh[n], acc[m][n]);
        acc[m][n] = mfma16(a[m], bl[n], acc[m][n]);
      }
    __syncthreads();   // drains vmcnt(0): next buffer fully staged; reads of cur done
    cur ^= 1;
  }
  #pragma unroll
  for(int m=0;m<4;m++)
    #pragma unroll
    for(int n=0;n<4;n++)
      #pragma unroll
      for(int r=0;r<4;r++){
        int gm = m0 + wr*64 + m*16 + lk*4 + r;
        int gn = n0 + wc*64 + n*16 + lr;
        float v = acc[m][n][r];
        if(EPI==1){ v += bias[gn]; v = 0.5f*v*(1.f + erff(v*0.70710678118f)); }
        if(OF32) ((float*)Cp)[(size_t)gm*N + gn] = v;
        else     ((bf16*)Cp)[(size_t)gm*N + gn] = f2b(v);
      }
}

// ---------------- beta = sigmoid(hs @ Wb), hs f32 ----------------
__global__ __launch_bounds__(256) void k_beta(const float* __restrict__ X, const float* __restrict__ Wb,
                                              float* __restrict__ beta){
  int row = blockIdx.x*4 + (threadIdx.x>>6), lane = threadIdx.x&63;
  const float* xp = X + (size_t)row*HH;
  float a0=0,a1=0,a2=0,a3=0;
  for(int k=lane;k<HH;k+=64){
    float x = xp[k];
    float4 wr = *(const float4*)(Wb + (size_t)k*4);
    a0 += x*wr.x; a1 += x*wr.y; a2 += x*wr.z; a3 += x*wr.w;
  }
  #pragma unroll
  for(int off=32;off>=1;off>>=1){
    a0 += __shfl_down(a0,off,64); a1 += __shfl_down(a1,off,64);
    a2 += __shfl_down(a2,off,64); a3 += __shfl_down(a3,off,64);
  }
  if(lane==0){
    beta[(size_t)row*4+0] = 1.f/(1.f+__expf(-a0));
    beta[(size_t)row*4+1] = 1.f/(1.f+__expf(-a1));
    beta[(size_t)row*4+2] = 1.f/(1.f+__expf(-a2));
    beta[(size_t)row*4+3] = 1.f/(1.f+__expf(-a3));
  }
}

// ---------------- depthwise causal conv K=4 + silu (+ per-head l2norm) ----------------
__global__ __launch_bounds__(256) void k_conv4(const bf16* __restrict__ pre, const float* __restrict__ filt,
                                               bf16* __restrict__ outp, int do_norm){
  __shared__ float red[4][8];
  int tx = threadIdx.x, head = blockIdx.y, b = blockIdx.z; int l0 = blockIdx.x*64;
  int wv = tx>>6, lane = tx&63;
  int c = head*256 + tx;
  const bf16* p = pre + (size_t)b*LL*HH + c;
  const float* fp = filt + (size_t)c*4;
  float f0=fp[0], f1=fp[1], f2=fp[2], f3=fp[3];
  float x0,x1,x2;
  if(l0>0){ x0=b2f(p[(size_t)(l0-3)*HH]); x1=b2f(p[(size_t)(l0-2)*HH]); x2=b2f(p[(size_t)(l0-1)*HH]); }
  else { x0=x1=x2=0.f; }
  for(int g=0; g<8; g++){
    float y[8];
    #pragma unroll
    for(int i=0;i<8;i++){
      int l = l0+g*8+i;
      float x3 = b2f(p[(size_t)l*HH]);
      float u = f0*x0 + f1*x1 + f2*x2 + f3*x3;
      x0=x1; x1=x2; x2=x3;
      y[i] = u/(1.f+__expf(-u));
    }
    if(do_norm){
      float sq[8];
      #pragma unroll
      for(int i=0;i<8;i++) sq[i]=y[i]*y[i];
      #pragma unroll
      for(int off=32;off>=1;off>>=1)
        #pragma unroll
        for(int i=0;i<8;i++) sq[i] += __shfl_down(sq[i],off,64);
      if(lane==0){
        #pragma unroll
        for(int i=0;i<8;i++) red[wv][i]=sq[i];
      }
      __syncthreads();
      float tot[8];
      #pragma unroll
      for(int i=0;i<8;i++) tot[i]=red[0][i]+red[1][i]+red[2][i]+red[3][i];
      __syncthreads();
      #pragma unroll
      for(int i=0;i<8;i++) y[i] *= rsqrtf(tot[i]);
    }
    #pragma unroll
    for(int i=0;i<8;i++) outp[(size_t)(b*LL + l0+g*8+i)*HH + c] = f2b(y[i]);
  }
}

// ---------------- gate: softmax4(h1 @ Wf2 + bf2), Wf2 f32 [2048][16] ----------------
__global__ __launch_bounds__(256) void k_gate(const bf16* __restrict__ h1, const float* __restrict__ W2,
                                              const float* __restrict__ bf2v, float* __restrict__ fw){
  int row = blockIdx.x*4 + (threadIdx.x>>6), lane = threadIdx.x&63;
  const bf16* hp = h1 + (size_t)row*2048;
  float acc[16];
  #pragma unroll
  for(int c=0;c<16;c++) acc[c]=0.f;
  for(int k=lane;k<2048;k+=64){
    float x = b2f(hp[k]);
    const float* wr = W2 + (size_t)k*16;
    float4 w0 = *(const float4*)(wr), w1 = *(const float4*)(wr+4);
    float4 w2 = *(const float4*)(wr+8), w3 = *(const float4*)(wr+12);
    acc[0]+=x*w0.x; acc[1]+=x*w0.y; acc[2]+=x*w0.z; acc[3]+=x*w0.w;
    acc[4]+=x*w1.x; acc[5]+=x*w1.y; acc[6]+=x*w1.z; acc[7]+=x*w1.w;
    acc[8]+=x*w2.x; acc[9]+=x*w2.y; acc[10]+=x*w2.z; acc[11]+=x*w2.w;
    acc[12]+=x*w3.x; acc[13]+=x*w3.y; acc[14]+=x*w3.z; acc[15]+=x*w3.w;
  }
  #pragma unroll
  for(int off=32;off>=1;off>>=1)
    #pragma unroll
    for(int c=0;c<16;c++) acc[c] += __shfl_down(acc[c],off,64);
  if(lane==0){
    #pragma unroll
    for(int h=0;h<4;h++){
      float s0=acc[h*4+0]+bf2v[h*4+0], s1=acc[h*4+1]+bf2v[h*4+1];
      float s2=acc[h*4+2]+bf2v[h*4+2], s3=acc[h*4+3]+bf2v[h*4+3];
      float mx = fmaxf(fmaxf(s0,s1),fmaxf(s2,s3));
      float e0=__expf(s0-mx), e1=__expf(s1-mx), e2=__expf(s2-mx), e3=__expf(s3-mx);
      float inv = 1.f/(e0+e1+e2+e3);
      fw[(size_t)row*16+h*4+0]=e0*inv; fw[(size_t)row*16+h*4+1]=e1*inv;
      fw[(size_t)row*16+h*4+2]=e2*inv; fw[(size_t)row*16+h*4+3]=e3*inv;
    }
  }
}

// ---------------- per-chunk precompute (VALU): T, u, w, attn(bf16 hi/lo), kT ----------------
__global__ __launch_bounds__(256) void k_pre2(const bf16* __restrict__ qn, const bf16* __restrict__ kn,
    const bf16* __restrict__ vv, const float* __restrict__ beta,
    bf16* __restrict__ uFb, bf16* __restrict__ wFb, bf16* __restrict__ aFb, bf16* __restrict__ aFl,
    bf16* __restrict__ kTb){
  __shared__ __align__(16) bf16 qs[8192], ks[8192], vs[8192];
  __shared__ float T[32][33];
  __shared__ float bet[32];
  int ch = blockIdx.x, bh = blockIdx.y, b = bh>>2, h = bh&3;
  int t = threadIdx.x;
  int l0 = ch*32;
  size_t rowbase = ((size_t)(b*LL+l0))*HH + h*256;
  #pragma unroll
  for(int i=0;i<4;i++){
    int f = i*256+t, row = f>>5, sub = f&31;
    size_t go = rowbase + (size_t)row*HH + sub*8;
    *(bf16x8*)&qs[f*8] = *(const bf16x8*)(qn+go);
    *(bf16x8*)&ks[f*8] = *(const bf16x8*)(kn+go);
    *(bf16x8*)&vs[f*8] = *(const bf16x8*)(vv+go);
  }
  if(t<32) bet[t] = beta[(size_t)(b*LL+l0+t)*4 + h];
  __syncthreads();
  int c = t>>3, e0 = (t&7)*4;
  float d0=0,d1=0,d2=0,d3=0, a0=0,a1=0,a2=0,a3=0;
  for(int d=0; d<256; d++){
    float kc = b2f(ks[c*256+d]);
    float qc = b2f(qs[c*256+d]);
    float k0 = b2f(ks[(e0+0)*256+d]);
    float k1 = b2f(ks[(e0+1)*256+d]);
    float k2 = b2f(ks[(e0+2)*256+d]);
    float k3 = b2f(ks[(e0+3)*256+d]);
    d0 += kc*k0; d1 += kc*k1; d2 += kc*k2; d3 += kc*k3;
    a0 += qc*k0; a1 += qc*k1; a2 += qc*k2; a3 += qc*k3;
  }
  float bc = bet[c];
  T[c][e0+0] = (c>e0+0)? -bc*d0 : 0.f;
  T[c][e0+1] = (c>e0+1)? -bc*d1 : 0.f;
  T[c][e0+2] = (c>e0+2)? -bc*d2 : 0.f;
  T[c][e0+3] = (c>e0+3)? -bc*d3 : 0.f;
  size_t ab = ((size_t)(bh*NCH+ch))*1024;
  {
    float av[4] = { (c>=e0+0)? a0 : 0.f, (c>=e0+1)? a1 : 0.f,
                    (c>=e0+2)? a2 : 0.f, (c>=e0+3)? a3 : 0.f };
    #pragma unroll
    for(int i=0;i<4;i++){
      bf16 hb = f2b(av[i]);
      aFb[ab + c*32 + e0+i] = hb;
      aFl[ab + c*32 + e0+i] = f2b(av[i] - (float)hb);
    }
  }
  __syncthreads();
  // forward substitution — lanes 0..31 of wave 0, lockstep; volatile forces LDS traffic
  if(t < 32){
    volatile float (*Tv)[33] = (volatile float (*)[33])T;
    int j = t;
    for(int i=1;i<32;i++){
      float s2 = 0.f;
      for(int m=0;m<i;m++) s2 += Tv[i][m]*Tv[m][j];
      Tv[i][j] += s2;
    }
    Tv[j][j] += 1.f;
  }
  __syncthreads();
  int dv0 = (t&7)*32;
  float uacc[32], wacc[32];
  #pragma unroll
  for(int j=0;j<32;j++){ uacc[j]=0.f; wacc[j]=0.f; }
  for(int c2=0;c2<32;c2++){
    float coef = T[c][c2]*bet[c2];
    #pragma unroll
    for(int j=0;j<32;j++){
      uacc[j] += coef * b2f(vs[c2*256+dv0+j]);
      wacc[j] += coef * b2f(ks[c2*256+dv0+j]);
    }
  }
  size_t ub = ((size_t)(bh*NCH+ch))*8192 + (size_t)c*256 + dv0;
  #pragma unroll
  for(int j=0;j<32;j++){ uFb[ub+j] = f2b(uacc[j]); wFb[ub+j] = f2b(wacc[j]); }
  // kT emit: thread t owns dk=t, writes kT[dk][0..31] (A-operand layout for S-update MFMA)
  {
    bf16* kout = kTb + ((size_t)(bh*NCH+ch))*8192 + (size_t)t*32;
    #pragma unroll
    for(int q8=0;q8<4;q8++){
      bf16x8 v8;
      #pragma unroll
      for(int i=0;i<8;i++) v8[i] = ks[(q8*8+i)*256 + t];
      *(bf16x8*)(kout + q8*8) = v8;
    }
  }
}

// ---------------- MFMA chunkwise scan, cross-chunk register prefetch ----------------
// 128 independent single-wave blocks; unit = (bh, 16-col dv-slice). (R8/R9: 8-wave
// co-location refuted — toolchain caps >256-thread blocks at 128 VGPR; and with only
// 128 waves of work, consolidating SIMDs cannot beat the 128-CU spread anyway.)
// No s_barrier (single wave) -> no compiler-forced vmcnt(0) drains -> next chunk's global
// operands (w,q,kT,attn,u) prefetched into register arrays. R10: fences relaxed to
// waitcnt+memory-clobber only (no sched_barrier) — scheduler may overlap across phases.
__global__ __launch_bounds__(64,1) void k_scan4(const bf16* __restrict__ qn,
    const bf16* __restrict__ wFb, const bf16* __restrict__ uFb,
    const bf16* __restrict__ kTb, const bf16* __restrict__ aFb, const bf16* __restrict__ aFl,
    bf16* __restrict__ delta){
  __shared__ __align__(16) char STh[8192], STl[8192];  // bf16 [j=16][dk=256], off ^= ((j&7)<<4)
  __shared__ __align__(16) char UTh[1024], UTl[1024];  // bf16 [j=16][c2=32],  off ^= ((j&3)<<4)
  int l = threadIdx.x;
  int bh = blockIdx.x & 7, js = blockIdx.x >> 3;   // XCD swizzle: 16 dv-slices of one bh share an L2
  int b = bh>>2, h = bh&3;
  int lr = l & 15, lk = l >> 4;
  int jb = js*16;
  float4 z4 = make_float4(0.f,0.f,0.f,0.f);
  #pragma unroll
  for(int i=0;i<8;i++){ ((float4*)STh)[l+i*64] = z4; ((float4*)STl)[l+i*64] = z4; }
  LDS_WAIT();
  f32x4 Sacc[16];
  #pragma unroll
  for(int i=0;i<16;i++) Sacc[i] = f32x4{0.f,0.f,0.f,0.f};
  const int Xst = (lr&7)<<4;   // ST row swizzle (bits 4-6 of FULL in-row byte offset, rule #21)
  const int Xut = (lr&3)<<4;   // UT row swizzle (bits 4-5)
  const bf16* wp  = wFb + (size_t)bh*NCH*8192;
  const bf16* up  = uFb + (size_t)bh*NCH*8192;
  const bf16* kp  = kTb + (size_t)bh*NCH*8192;
  const bf16* aph = aFb + (size_t)bh*NCH*1024;
  const bf16* apl = aFl + (size_t)bh*NCH*1024;
  const bf16* qp  = qn + (size_t)b*LL*HH + h*256;
  // prefetch registers (chunk 0)
  s16x8 Wr[16], Qr[16], Kr[16], A0h, A1h, A0l, A1l;
  bf16 Ur[8];
  #pragma unroll
  for(int t8=0;t8<8;t8++){
    Wr[t8]   = ldg8(wp + lr*256      + t8*32 + lk*8);
    Wr[8+t8] = ldg8(wp + (16+lr)*256 + t8*32 + lk*8);
    Qr[t8]   = ldg8(qp + (size_t)lr*HH      + t8*32 + lk*8);
    Qr[8+t8] = ldg8(qp + (size_t)(16+lr)*HH + t8*32 + lk*8);
  }
  #pragma unroll
  for(int dt=0;dt<16;dt++) Kr[dt] = ldg8(kp + (dt*16+lr)*32 + lk*8);
  A0h = ldg8(aph + lr*32 + lk*8); A1h = ldg8(aph + (16+lr)*32 + lk*8);
  A0l = ldg8(apl + lr*32 + lk*8); A1l = ldg8(apl + (16+lr)*32 + lk*8);
  #pragma unroll
  for(int r8=0;r8<8;r8++){
    int rr = (r8>>2)*16 + lk*4 + (r8&3);
    Ur[r8] = up[(size_t)rr*256 + jb + lr];
  }
  for(int ci=0; ci<NCH; ci++){
    size_t nxw = (ci<NCH-1)? 8192 : 0;            // next-chunk strides (clamped at tail)
    size_t nxa = (ci<NCH-1)? 1024 : 0;
    size_t nxq = (ci<NCH-1)? (size_t)32*HH : 0;
    // ---- Phase 1: ST fragments to regs, then the 64-MFMA block
    s16x8 sth[8], stl[8];
    #pragma unroll
    for(int t8=0;t8<8;t8++){
      int ro = lr*512 + ((t8*64 + lk*16) ^ Xst);
      sth[t8] = *(const s16x8*)(STh + ro);
      stl[t8] = *(const s16x8*)(STl + ro);
    }
    f32x4 wh0={0.f,0.f,0.f,0.f}, wl0=wh0, wh1=wh0, wl1=wh0;
    f32x4 qh0=wh0, ql0=wh0, qh1=wh0, ql1=wh0;
    #pragma unroll
    for(int t8=0;t8<8;t8++){
      wh0 = mfma16(Wr[t8],   sth[t8], wh0); wl0 = mfma16(Wr[t8],   stl[t8], wl0);
      wh1 = mfma16(Wr[8+t8], sth[t8], wh1); wl1 = mfma16(Wr[8+t8], stl[t8], wl1);
      qh0 = mfma16(Qr[t8],   sth[t8], qh0); ql0 = mfma16(Qr[t8],   stl[t8], ql0);
      qh1 = mfma16(Qr[8+t8], sth[t8], qh1); ql1 = mfma16(Qr[8+t8], stl[t8], ql1);
    }
    f32x4 ws0 = wh0+wl0, ws1 = wh1+wl1;
    f32x4 qs0 = qh0+ql0, qs1 = qh1+ql1;
    // prefetch next W,Q (regs fully consumed above)
    #pragma unroll
    for(int t8=0;t8<8;t8++){
      Wr[t8]   = ldg8(wp + nxw + lr*256      + t8*32 + lk*8);
      Wr[8+t8] = ldg8(wp + nxw + (16+lr)*256 + t8*32 + lk*8);
      Qr[t8]   = ldg8(qp + nxq + (size_t)lr*HH      + t8*32 + lk*8);
      Qr[8+t8] = ldg8(qp + nxq + (size_t)(16+lr)*HH + t8*32 + lk*8);
    }
    // ---- Phase 2: u_t = u - wS -> UT hi/lo (lane holds (c=ct*16+lk*4+r, j=lr))
    #pragma unroll
    for(int ct=0;ct<2;ct++){
      f32x4 w = ct? ws1 : ws0;
      bf16x4 hh, llo;
      #pragma unroll
      for(int r=0;r<4;r++){
        float v = b2f(Ur[ct*4+r]) - w[r];
        bf16 hb = f2b(v); hh[r]=hb; llo[r]=f2b(v-(float)hb);
      }
      int utw = lr*64 + ((ct*32 + lk*8) ^ Xut);
      *(bf16x4*)(UTh+utw)=hh; *(bf16x4*)(UTl+utw)=llo;
    }
    #pragma unroll
    for(int r8=0;r8<8;r8++){
      int rr = (r8>>2)*16 + lk*4 + (r8&3);
      Ur[r8] = up[nxw + (size_t)rr*256 + jb + lr];
    }
    LDS_WAIT();   // cross-lane UT handoff (single wave: lgkmcnt suffices, no barrier)
    int utR = lr*64 + ((lk*16) ^ Xut);
    s16x8 th = *(const s16x8*)(UTh + utR);
    s16x8 tl = *(const s16x8*)(UTl + utR);
    // ---- Phase 3: o = qS + attn@u_t
    qs0 = mfma16(A0h, th, qs0); qs0 = mfma16(A0h, tl, qs0); qs0 = mfma16(A0l, th, qs0);
    qs1 = mfma16(A1h, th, qs1); qs1 = mfma16(A1h, tl, qs1); qs1 = mfma16(A1l, th, qs1);
    bf16* dp = delta + ((size_t)(b*LL + ci*32))*HH + h*256 + jb + lr;
    #pragma unroll
    for(int ct=0;ct<2;ct++){
      f32x4 o = ct? qs1 : qs0;
      #pragma unroll
      for(int r=0;r<4;r++) dp[(size_t)(ct*16 + lk*4 + r)*HH] = f2b(o[r]);
    }
    A0h = ldg8(aph + nxa + lr*32 + lk*8); A1h = ldg8(aph + nxa + (16+lr)*32 + lk*8);
    A0l = ldg8(apl + nxa + lr*32 + lk*8); A1l = ldg8(apl + nxa + (16+lr)*32 + lk*8);
    // ---- Phase 4: S[dk][j] += k^T @ u_t
    #pragma unroll
    for(int dt=0;dt<16;dt++){
      Sacc[dt] = mfma16(Kr[dt], th, Sacc[dt]);
      Sacc[dt] = mfma16(Kr[dt], tl, Sacc[dt]);
    }
    #pragma unroll
    for(int dt=0;dt<16;dt++) Kr[dt] = ldg8(kp + nxw + (size_t)(dt*16+lr)*32 + lk*8);
    // ---- Phase 5: restage S -> LDS bf16 hi/lo
    #pragma unroll
    for(int dt=0;dt<16;dt++){
      bf16x4 hh, llo;
      #pragma unroll
      for(int r=0;r<4;r++){
        float v = Sacc[dt][r];
        bf16 hb=f2b(v); hh[r]=hb; llo[r]=f2b(v-(float)hb);
      }
      int stw = lr*512 + ((dt*32 + lk*8) ^ Xst);
      *(bf16x4*)(STh+stw)=hh; *(bf16x4*)(STl+stw)=llo;
    }
    LDS_WAIT();   // S restage visible before next chunk's phase-1 reads
    wp += nxw; up += nxw; kp += nxw; aph += nxa; apl += nxa; qp += nxq;
  }
}

// ---------------- FIR convs + gated fusion + RMSNorm ----------------
__global__ __launch_bounds__(256) void k_fuse(const bf16* __restrict__ vv, const bf16* __restrict__ delta,
    const float* __restrict__ fw, const float* __restrict__ fsw, const float* __restrict__ flw,
    const float* __restrict__ rmsw, bf16* __restrict__ fused){
  __shared__ float red[4][8];
  int tx = threadIdx.x, head = blockIdx.y, b = blockIdx.z; int l0 = blockIdx.x*64;
  int wv = tx>>6, lane = tx&63;
  int c = head*256 + tx;
  const bf16* vp = vv + (size_t)b*LL*HH + c;
  float fs[7], fl[64];
  #pragma unroll
  for(int j=0;j<7;j++) fs[j] = fsw[(size_t)c*7+j];
  #pragma unroll
  for(int j=0;j<64;j++) fl[j] = flw[(size_t)c*64+j];
  float win[64];
  #pragma unroll
  for(int i=0;i<63;i++){ int l=l0-63+i; win[i] = (l>=0)? b2f(vp[(size_t)l*HH]) : 0.f; }
  float rw = rmsw[tx];
  for(int g=0; g<8; g++){
    float oo[8], sq[8];
    #pragma unroll
    for(int i=0;i<8;i++){
      int s = g*8+i; int l = l0+s;
      win[(s+63)&63] = b2f(vp[(size_t)l*HH]);
      float ll2 = 0.f;
      #pragma unroll
      for(int tp=0;tp<64;tp++) ll2 += fl[tp]*win[(s+tp)&63];
      float ls = 0.f;
      #pragma unroll
      for(int tp=0;tp<7;tp++) ls += fs[tp]*win[(s+57+tp)&63];
      float dl = b2f(delta[(size_t)(b*LL+l)*HH + c]);
      float vh = win[(s+63)&63];
      const float* fp = fw + (size_t)(b*LL+l)*16 + head*4;
      float o = fp[0]*ls + fp[1]*ll2 + fp[2]*dl + fp[3]*vh;
      oo[i]=o; sq[i]=o*o;
    }
    #pragma unroll
    for(int off=32;off>=1;off>>=1)
      #pragma unroll
      for(int i=0;i<8;i++) sq[i] += __shfl_down(sq[i],off,64);
    if(lane==0){
      #pragma unroll
      for(int i=0;i<8;i++) red[wv][i]=sq[i];
    }
    __syncthreads();
    float tot[8];
    #pragma unroll
    for(int i=0;i<8;i++) tot[i]=red[0][i]+red[1][i]+red[2][i]+red[3][i];
    __syncthreads();
    #pragma unroll
    for(int i=0;i<8;i++){
      int l = l0+g*8+i;
      fused[(size_t)(b*LL+l)*HH + c] = f2b(oo[i]*rsqrtf(tot[i]*(1.f/256.f)+1e-5f)*rw);
    }
  }
}

extern "C" void kernel_launch(void* const* d_in, const int* in_sizes, int n_in,
                              void* d_out, int out_size, void* d_ws, size_t ws_size,
                              hipStream_t stream){
  const float* hs  =(const float*)d_in[0];
  const float* Wq  =(const float*)d_in[1];
  const float* Wk  =(const float*)d_in[2];
  const float* Wv  =(const float*)d_in[3];
  const float* Wb  =(const float*)d_in[4];
  const float* cqw =(const float*)d_in[5];
  const float* ckw =(const float*)d_in[6];
  const float* cvw =(const float*)d_in[7];
  const float* fsw =(const float*)d_in[8];
  const float* flw =(const float*)d_in[9];
  const float* Wf1 =(const float*)d_in[10];
  const float* bf1 =(const float*)d_in[11];
  const float* Wf2 =(const float*)d_in[12];
  const float* bf2v=(const float*)d_in[13];
  const float* rmsw=(const float*)d_in[14];
  const float* Wo  =(const float*)d_in[15];

  char* ws = (char*)d_ws;
  size_t off = 0;
  auto alloc = [&](size_t bytes)->char*{
    char* p = ws + off; off = (off + bytes + 255) & ~(size_t)255; return p;
  };
  bf16* pre   = (bf16*)alloc(8192ull*1024*2);   // q/k/v pre-conv (sequential); later kTb; later fusedb
  bf16* qn    = (bf16*)alloc(8192ull*1024*2);
  bf16* kn    = (bf16*)alloc(8192ull*1024*2);
  bf16* vvb   = (bf16*)alloc(8192ull*1024*2);
  float* beta = (float*)alloc(8192ull*4*4);
  bf16* uFb   = (bf16*)alloc(8ull*128*8192*2);  // h1 aliases uFb+wFb (32MB) before k_pre2
  bf16* wFb   = (bf16*)alloc(8ull*128*8192*2);
  bf16* aFb   = (bf16*)alloc(8ull*128*1024*4);  // hi (2MB) + lo (2MB) attn, bf16
  float* fw   = (float*)alloc(8192ull*16*4);
  bf16* aFl   = aFb + 8ull*128*1024;
  bf16* h1    = uFb;                            // dead once fw extracted
  bf16* kTb   = pre;                            // pre dead after conv-v; dead again before k_fuse
  bf16* dlt   = (bf16*)d_out;                   // first 16MB of the 32MB f32 out; dead before final GEMM
  bf16* fusedb= pre;
  float* outb = (float*)d_out;
  // aliased staging (no extra workspace):
  //  - hsb (bf16 hs, 16MB): vvb-space — vvb is only written by conv-v, the LAST hs consumer ran
  //  - WT(Wf1) 8MB: qn-space (qn written by conv-q, after the gate GEMM)
  //  - WT(Wq/Wk/Wv/Wo) 4MB: uFb-space (dead between k_gate and k_pre2, and after k_scan4)
  bf16* hsb  = vvb;
  bf16* WT1h = qn;            bf16* WT1l = qn + 2048ull*1024;
  bf16* WTh  = uFb;           bf16* WTl  = uFb + 1024ull*1024;

  dim3 b256(256);
  // hs -> bf16 once
  k_h2b<<<dim3(4096), b256, 0, stream>>>(hs, hsb);
  // gate path FIRST (h1 aliases uFb/wFb; WT(Wf1) lives in qn-space)
  k_wT<<<dim3(64,32), b256, 0, stream>>>(Wf1, WT1h, WT1l, 1024, 2048);
  k_gemm_m2<1,0><<<dim3(16,64), b256, 0, stream>>>(hsb, WT1h, WT1l, bf1, h1, 8192, 2048, 1024);
  k_gate<<<dim3(2048), b256, 0, stream>>>(h1, Wf2, bf2v, fw);
  // q path (WT in uFb-space, dead until k_pre2)
  k_wT<<<dim3(32,32), b256, 0, stream>>>(Wq, WTh, WTl, 1024, 1024);
  k_gemm_m2<0,0><<<dim3(8,64), b256, 0, stream>>>(hsb, WTh, WTl, nullptr, pre, 8192, 1024, 1024);
  k_conv4<<<dim3(64,4,2), b256, 0, stream>>>(pre, cqw, qn, 1);
  // k path
  k_wT<<<dim3(32,32), b256, 0, stream>>>(Wk, WTh, WTl, 1024, 1024);
  k_gemm_m2<0,0><<<dim3(8,64), b256, 0, stream>>>(hsb, WTh, WTl, nullptr, pre, 8192, 1024, 1024);
  k_conv4<<<dim3(64,4,2), b256, 0, stream>>>(pre, ckw, kn, 1);
  // v path (last hsb use, then conv-v overwrites hsb with vvb)
  k_wT<<<dim3(32,32), b256, 0, stream>>>(Wv, WTh, WTl, 1024, 1024);
  k_gemm_m2<0,0><<<dim3(8,64), b256, 0, stream>>>(hsb, WTh, WTl, nullptr, pre, 8192, 1024, 1024);
  k_conv4<<<dim3(64,4,2), b256, 0, stream>>>(pre, cvw, vvb, 0);
  // beta (reads hs f32)
  k_beta<<<dim3(2048), b256, 0, stream>>>(hs, Wb, beta);
  // delta rule (overwrites uFb/wFb — WT dead)
  k_pre2<<<dim3(128,8), b256, 0, stream>>>(qn, kn, vvb, beta, uFb, wFb, aFb, aFl, kTb);
  k_scan4<<<dim3(128), dim3(64), 0, stream>>>(qn, wFb, uFb, kTb, aFb, aFl, dlt);
  // fuse + output projection (f32 out); WT(Wo) in uFb-space (dead after scan)
  k_fuse<<<dim3(64,4,2), b256, 0, stream>>>(vvb, dlt, fw, fsw, flw, rmsw, fusedb);
  k_wT<<<dim3(32,32), b256, 0, stream>>>(Wo, WTh, WTl, 1024, 1024);
  k_gemm_m2<0,1><<<dim3(8,64), b256, 0, stream>>>(fusedb, WTh, WTl, nullptr, outb, 8192, 1024, 1024);

  (void)in_sizes; (void)n_in; (void)out_size; (void)ws_size;
}

// Round 12
// 1143.798 us; speedup vs baseline: 3.1791x; 1.0803x over previous
//
#include <hip/hip_runtime.h>
#include <cstdint>

typedef __bf16 bf16;
typedef __bf16 bf16x8 __attribute__((ext_vector_type(8)));
typedef __bf16 bf16x4 __attribute__((ext_vector_type(4)));
typedef short  s16x8  __attribute__((ext_vector_type(8)));
typedef float  f32x4  __attribute__((ext_vector_type(4)));

#define DEV __device__ __forceinline__

static const int LL = 4096, HH = 1024, NCH = 128;

DEV float b2f(bf16 x){ return (float)x; }
DEV bf16  f2b(float x){ return (bf16)x; }
DEV f32x4 mfma16(s16x8 a, s16x8 b, f32x4 c){
  return __builtin_amdgcn_mfma_f32_16x16x32_bf16(a, b, c, 0, 0, 0);
}
DEV s16x8 ldg8(const bf16* p){ return *(const s16x8*)p; }

// async global->LDS, 16B per lane (CK idiom: int->as(3)/as(1) via uintptr_t, no addrspacecast)
DEV void gld16(const bf16* g, bf16* l){
  auto* lp = reinterpret_cast<__attribute__((address_space(3))) uint32_t*>(
      reinterpret_cast<uintptr_t>(l));
  auto* gp = reinterpret_cast<const __attribute__((address_space(1))) uint32_t*>(
      reinterpret_cast<uintptr_t>(g));
  __builtin_amdgcn_global_load_lds(gp, lp, 16, 0, 0);
}

// single-wave LDS handoff: lgkmcnt drain + scheduling fence.
// R11 A/B RESULT: with sched_barrier = 322us, without = 357us (+VGPR 244) — the
// scheduler's reordering across the fence HURT. Keep the full fence (rule #18 form).
// NOT __syncthreads(): hipcc prepends s_waitcnt vmcnt(0) to s_barrier, which would
// drain the cross-chunk global prefetch (R2 post-mortem).
#define LDS_FENCE() do { asm volatile("s_waitcnt lgkmcnt(0)" ::: "memory"); \
                         __builtin_amdgcn_sched_barrier(0); } while(0)

// ---------------- hs f32 -> bf16 (once; all GEMM A-reads become bf16) ----------------
__global__ __launch_bounds__(256) void k_h2b(const float* __restrict__ X, bf16* __restrict__ Y){
  size_t i = ((size_t)blockIdx.x*256 + threadIdx.x)*8;
  float4 a = *(const float4*)(X+i), b = *(const float4*)(X+i+4);
  bf16x8 v;
  v[0]=f2b(a.x); v[1]=f2b(a.y); v[2]=f2b(a.z); v[3]=f2b(a.w);
  v[4]=f2b(b.x); v[5]=f2b(b.y); v[6]=f2b(b.z); v[7]=f2b(b.w);
  *(bf16x8*)(Y+i) = v;
}

// ---------------- weight transpose: W[K][N] f32 -> WT[N][K] bf16 (R12: hi only) ----------------
__global__ __launch_bounds__(256) void k_wT(const float* __restrict__ W, bf16* __restrict__ Th,
                                            int K, int N){
  __shared__ float Ts[32][33];
  int t = threadIdx.x;
  int ni = blockIdx.x*32, ki = blockIdx.y*32;
  int r = t>>3, c4 = (t&7)*4;
  float4 v = *(const float4*)(W + (size_t)(ki+r)*N + ni + c4);
  Ts[r][c4+0]=v.x; Ts[r][c4+1]=v.y; Ts[r][c4+2]=v.z; Ts[r][c4+3]=v.w;
  __syncthreads();
  bf16x4 hh;
  #pragma unroll
  for(int i=0;i<4;i++) hh[i] = f2b(Ts[c4+i][r]);
  *(bf16x4*)(Th + (size_t)(ni+r)*K + ki + c4) = hh;
}

// ---------------- MFMA GEMM v3: A bf16 [M][K]; B as BT[N][K] bf16 ----------------
// R12: B lo-term dropped (weights plain bf16) — halves MFMA (16/K-step/wave), cuts LDS
// staging from 3 arrays to 2. Error budget: B rounding ~ same order as A's existing bf16
// rounding; absmax headroom 0.0156 vs 0.0656 threshold.
// Double-buffered LDS staged by global_load_lds(16B): 1 barrier per K-step (its implicit
// vmcnt(0) drains the *next* tile's stage, issued before this step's compute -> overlap).
// Swizzle (rule #21): LDS dest linear (gload_lds requirement), global SOURCE column
// pre-XOR'd, read XOR'd — same involution both sides, bijective within the 64B row.
template<int EPI, int OF32>
__global__ __launch_bounds__(256) void k_gemm_m2(const bf16* __restrict__ A,
    const bf16* __restrict__ BTh,
    const float* __restrict__ bias, void* __restrict__ Cp, int M, int N, int K){
  __shared__ __align__(16) bf16 As [2][128*32];
  __shared__ __align__(16) bf16 Bsh[2][128*32];
  int t = threadIdx.x;
  int w = t>>6, ln = t&63, lr = ln&15, lk = ln>>4;
  int wr = w>>1, wc = w&1;
  int m0 = blockIdx.y*128, n0 = blockIdx.x*128;
  f32x4 acc[4][4];
  #pragma unroll
  for(int m=0;m<4;m++)
    #pragma unroll
    for(int n=0;n<4;n++) acc[m][n] = f32x4{0.f,0.f,0.f,0.f};
  // stage geometry: per wave 2 instrs/array, instr j covers rows w*32+j*16 .. +15
  int srow[2], gcb[2];
  #pragma unroll
  for(int j=0;j<2;j++){
    srow[j] = w*32 + j*16 + (ln>>2);
    gcb[j]  = (ln&3) ^ (srow[j]&3);        // pre-swizzled source column block
  }
  auto STAGE = [&](int buf, int k0){
    #pragma unroll
    for(int j=0;j<2;j++){
      bf16* lb = &As[buf][(w*32+j*16)*32];  // wave-uniform base; HW adds lane*16
      gld16(A   + (size_t)(m0+srow[j])*K + k0 + gcb[j]*8, lb);
      lb = &Bsh[buf][(w*32+j*16)*32];
      gld16(BTh + (size_t)(n0+srow[j])*K + k0 + gcb[j]*8, lb);
    }
  };
  STAGE(0, 0);
  __syncthreads();
  int cur = 0;
  for(int k0=0;k0<K;k0+=32){
    if(k0+32<K) STAGE(cur^1, k0+32);
    s16x8 a[4], bh[4];
    #pragma unroll
    for(int m=0;m<4;m++){
      int row = wr*64 + m*16 + lr;
      a[m] = *(const s16x8*)((char*)As[cur] + row*64 + ((lk*16) ^ ((lr&3)<<4)));
    }
    #pragma unroll
    for(int n=0;n<4;n++){
      int row = wc*64 + n*16 + lr;
      bh[n] = *(const s16x8*)((char*)Bsh[cur] + row*64 + ((lk*16) ^ ((lr&3)<<4)));
    }
    #pragma unroll
    for(int m=0;m<4;m++)
      #pragma unroll
      for(int n=0;n<4;n++)
        acc[m][n] = mfma16(a[m], bh[n], acc[m][n]);
    __syncthreads();   // drains vmcnt(0): next buffer fully staged; reads of cur done
    cur ^= 1;
  }
  #pragma unroll
  for(int m=0;m<4;m++)
    #pragma unroll
    for(int n=0;n<4;n++)
      #pragma unroll
      for(int r=0;r<4;r++){
        int gm = m0 + wr*64 + m*16 + lk*4 + r;
        int gn = n0 + wc*64 + n*16 + lr;
        float v = acc[m][n][r];
        if(EPI==1){ v += bias[gn]; v = 0.5f*v*(1.f + erff(v*0.70710678118f)); }
        if(OF32) ((float*)Cp)[(size_t)gm*N + gn] = v;
        else     ((bf16*)Cp)[(size_t)gm*N + gn] = f2b(v);
      }
}

// ---------------- beta = sigmoid(hs @ Wb), hs f32 ----------------
__global__ __launch_bounds__(256) void k_beta(const float* __restrict__ X, const float* __restrict__ Wb,
                                              float* __restrict__ beta){
  int row = blockIdx.x*4 + (threadIdx.x>>6), lane = threadIdx.x&63;
  const float* xp = X + (size_t)row*HH;
  float a0=0,a1=0,a2=0,a3=0;
  for(int k=lane;k<HH;k+=64){
    float x = xp[k];
    float4 wr = *(const float4*)(Wb + (size_t)k*4);
    a0 += x*wr.x; a1 += x*wr.y; a2 += x*wr.z; a3 += x*wr.w;
  }
  #pragma unroll
  for(int off=32;off>=1;off>>=1){
    a0 += __shfl_down(a0,off,64); a1 += __shfl_down(a1,off,64);
    a2 += __shfl_down(a2,off,64); a3 += __shfl_down(a3,off,64);
  }
  if(lane==0){
    beta[(size_t)row*4+0] = 1.f/(1.f+__expf(-a0));
    beta[(size_t)row*4+1] = 1.f/(1.f+__expf(-a1));
    beta[(size_t)row*4+2] = 1.f/(1.f+__expf(-a2));
    beta[(size_t)row*4+3] = 1.f/(1.f+__expf(-a3));
  }
}

// ---------------- depthwise causal conv K=4 + silu (+ per-head l2norm) ----------------
__global__ __launch_bounds__(256) void k_conv4(const bf16* __restrict__ pre, const float* __restrict__ filt,
                                               bf16* __restrict__ outp, int do_norm){
  __shared__ float red[4][8];
  int tx = threadIdx.x, head = blockIdx.y, b = blockIdx.z; int l0 = blockIdx.x*64;
  int wv = tx>>6, lane = tx&63;
  int c = head*256 + tx;
  const bf16* p = pre + (size_t)b*LL*HH + c;
  const float* fp = filt + (size_t)c*4;
  float f0=fp[0], f1=fp[1], f2=fp[2], f3=fp[3];
  float x0,x1,x2;
  if(l0>0){ x0=b2f(p[(size_t)(l0-3)*HH]); x1=b2f(p[(size_t)(l0-2)*HH]); x2=b2f(p[(size_t)(l0-1)*HH]); }
  else { x0=x1=x2=0.f; }
  for(int g=0; g<8; g++){
    float y[8];
    #pragma unroll
    for(int i=0;i<8;i++){
      int l = l0+g*8+i;
      float x3 = b2f(p[(size_t)l*HH]);
      float u = f0*x0 + f1*x1 + f2*x2 + f3*x3;
      x0=x1; x1=x2; x2=x3;
      y[i] = u/(1.f+__expf(-u));
    }
    if(do_norm){
      float sq[8];
      #pragma unroll
      for(int i=0;i<8;i++) sq[i]=y[i]*y[i];
      #pragma unroll
      for(int off=32;off>=1;off>>=1)
        #pragma unroll
        for(int i=0;i<8;i++) sq[i] += __shfl_down(sq[i],off,64);
      if(lane==0){
        #pragma unroll
        for(int i=0;i<8;i++) red[wv][i]=sq[i];
      }
      __syncthreads();
      float tot[8];
      #pragma unroll
      for(int i=0;i<8;i++) tot[i]=red[0][i]+red[1][i]+red[2][i]+red[3][i];
      __syncthreads();
      #pragma unroll
      for(int i=0;i<8;i++) y[i] *= rsqrtf(tot[i]);
    }
    #pragma unroll
    for(int i=0;i<8;i++) outp[(size_t)(b*LL + l0+g*8+i)*HH + c] = f2b(y[i]);
  }
}

// ---------------- gate: softmax4(h1 @ Wf2 + bf2), Wf2 f32 [2048][16] ----------------
__global__ __launch_bounds__(256) void k_gate(const bf16* __restrict__ h1, const float* __restrict__ W2,
                                              const float* __restrict__ bf2v, float* __restrict__ fw){
  int row = blockIdx.x*4 + (threadIdx.x>>6), lane = threadIdx.x&63;
  const bf16* hp = h1 + (size_t)row*2048;
  float acc[16];
  #pragma unroll
  for(int c=0;c<16;c++) acc[c]=0.f;
  for(int k=lane;k<2048;k+=64){
    float x = b2f(hp[k]);
    const float* wr = W2 + (size_t)k*16;
    float4 w0 = *(const float4*)(wr), w1 = *(const float4*)(wr+4);
    float4 w2 = *(const float4*)(wr+8), w3 = *(const float4*)(wr+12);
    acc[0]+=x*w0.x; acc[1]+=x*w0.y; acc[2]+=x*w0.z; acc[3]+=x*w0.w;
    acc[4]+=x*w1.x; acc[5]+=x*w1.y; acc[6]+=x*w1.z; acc[7]+=x*w1.w;
    acc[8]+=x*w2.x; acc[9]+=x*w2.y; acc[10]+=x*w2.z; acc[11]+=x*w2.w;
    acc[12]+=x*w3.x; acc[13]+=x*w3.y; acc[14]+=x*w3.z; acc[15]+=x*w3.w;
  }
  #pragma unroll
  for(int off=32;off>=1;off>>=1)
    #pragma unroll
    for(int c=0;c<16;c++) acc[c] += __shfl_down(acc[c],off,64);
  if(lane==0){
    #pragma unroll
    for(int h=0;h<4;h++){
      float s0=acc[h*4+0]+bf2v[h*4+0], s1=acc[h*4+1]+bf2v[h*4+1];
      float s2=acc[h*4+2]+bf2v[h*4+2], s3=acc[h*4+3]+bf2v[h*4+3];
      float mx = fmaxf(fmaxf(s0,s1),fmaxf(s2,s3));
      float e0=__expf(s0-mx), e1=__expf(s1-mx), e2=__expf(s2-mx), e3=__expf(s3-mx);
      float inv = 1.f/(e0+e1+e2+e3);
      fw[(size_t)row*16+h*4+0]=e0*inv; fw[(size_t)row*16+h*4+1]=e1*inv;
      fw[(size_t)row*16+h*4+2]=e2*inv; fw[(size_t)row*16+h*4+3]=e3*inv;
    }
  }
}

// ---------------- per-chunk precompute (VALU): T, u, w, attn(bf16 hi/lo), kT ----------------
__global__ __launch_bounds__(256) void k_pre2(const bf16* __restrict__ qn, const bf16* __restrict__ kn,
    const bf16* __restrict__ vv, const float* __restrict__ beta,
    bf16* __restrict__ uFb, bf16* __restrict__ wFb, bf16* __restrict__ aFb, bf16* __restrict__ aFl,
    bf16* __restrict__ kTb){
  __shared__ __align__(16) bf16 qs[8192], ks[8192], vs[8192];
  __shared__ float T[32][33];
  __shared__ float bet[32];
  int ch = blockIdx.x, bh = blockIdx.y, b = bh>>2, h = bh&3;
  int t = threadIdx.x;
  int l0 = ch*32;
  size_t rowbase = ((size_t)(b*LL+l0))*HH + h*256;
  #pragma unroll
  for(int i=0;i<4;i++){
    int f = i*256+t, row = f>>5, sub = f&31;
    size_t go = rowbase + (size_t)row*HH + sub*8;
    *(bf16x8*)&qs[f*8] = *(const bf16x8*)(qn+go);
    *(bf16x8*)&ks[f*8] = *(const bf16x8*)(kn+go);
    *(bf16x8*)&vs[f*8] = *(const bf16x8*)(vv+go);
  }
  if(t<32) bet[t] = beta[(size_t)(b*LL+l0+t)*4 + h];
  __syncthreads();
  int c = t>>3, e0 = (t&7)*4;
  float d0=0,d1=0,d2=0,d3=0, a0=0,a1=0,a2=0,a3=0;
  for(int d=0; d<256; d++){
    float kc = b2f(ks[c*256+d]);
    float qc = b2f(qs[c*256+d]);
    float k0 = b2f(ks[(e0+0)*256+d]);
    float k1 = b2f(ks[(e0+1)*256+d]);
    float k2 = b2f(ks[(e0+2)*256+d]);
    float k3 = b2f(ks[(e0+3)*256+d]);
    d0 += kc*k0; d1 += kc*k1; d2 += kc*k2; d3 += kc*k3;
    a0 += qc*k0; a1 += qc*k1; a2 += qc*k2; a3 += qc*k3;
  }
  float bc = bet[c];
  T[c][e0+0] = (c>e0+0)? -bc*d0 : 0.f;
  T[c][e0+1] = (c>e0+1)? -bc*d1 : 0.f;
  T[c][e0+2] = (c>e0+2)? -bc*d2 : 0.f;
  T[c][e0+3] = (c>e0+3)? -bc*d3 : 0.f;
  size_t ab = ((size_t)(bh*NCH+ch))*1024;
  {
    float av[4] = { (c>=e0+0)? a0 : 0.f, (c>=e0+1)? a1 : 0.f,
                    (c>=e0+2)? a2 : 0.f, (c>=e0+3)? a3 : 0.f };
    #pragma unroll
    for(int i=0;i<4;i++){
      bf16 hb = f2b(av[i]);
      aFb[ab + c*32 + e0+i] = hb;
      aFl[ab + c*32 + e0+i] = f2b(av[i] - (float)hb);
    }
  }
  __syncthreads();
  // forward substitution — lanes 0..31 of wave 0, lockstep; volatile forces LDS traffic
  if(t < 32){
    volatile float (*Tv)[33] = (volatile float (*)[33])T;
    int j = t;
    for(int i=1;i<32;i++){
      float s2 = 0.f;
      for(int m=0;m<i;m++) s2 += Tv[i][m]*Tv[m][j];
      Tv[i][j] += s2;
    }
    Tv[j][j] += 1.f;
  }
  __syncthreads();
  int dv0 = (t&7)*32;
  float uacc[32], wacc[32];
  #pragma unroll
  for(int j=0;j<32;j++){ uacc[j]=0.f; wacc[j]=0.f; }
  for(int c2=0;c2<32;c2++){
    float coef = T[c][c2]*bet[c2];
    #pragma unroll
    for(int j=0;j<32;j++){
      uacc[j] += coef * b2f(vs[c2*256+dv0+j]);
      wacc[j] += coef * b2f(ks[c2*256+dv0+j]);
    }
  }
  size_t ub = ((size_t)(bh*NCH+ch))*8192 + (size_t)c*256 + dv0;
  #pragma unroll
  for(int j=0;j<32;j++){ uFb[ub+j] = f2b(uacc[j]); wFb[ub+j] = f2b(wacc[j]); }
  // kT emit: thread t owns dk=t, writes kT[dk][0..31] (A-operand layout for S-update MFMA)
  {
    bf16* kout = kTb + ((size_t)(bh*NCH+ch))*8192 + (size_t)t*32;
    #pragma unroll
    for(int q8=0;q8<4;q8++){
      bf16x8 v8;
      #pragma unroll
      for(int i=0;i<8;i++) v8[i] = ks[(q8*8+i)*256 + t];
      *(bf16x8*)(kout + q8*8) = v8;
    }
  }
}

// ---------------- MFMA chunkwise scan, cross-chunk register prefetch ----------------
// 128 independent single-wave blocks; unit = (bh, 16-col dv-slice).
// DECLARED DONE at ~322us: TLP refuted (R8/R9: >256-thread blocks cap at 128 VGPR;
// 128 waves can't beat the 128-CU spread), scheduling freedom refuted (R11: removing
// sched_barrier = +35us), ds-hoist null (R7). Latency floor at 1 wave/SIMD.
__global__ __launch_bounds__(64,1) void k_scan4(const bf16* __restrict__ qn,
    const bf16* __restrict__ wFb, const bf16* __restrict__ uFb,
    const bf16* __restrict__ kTb, const bf16* __restrict__ aFb, const bf16* __restrict__ aFl,
    bf16* __restrict__ delta){
  __shared__ __align__(16) char STh[8192], STl[8192];  // bf16 [j=16][dk=256], off ^= ((j&7)<<4)
  __shared__ __align__(16) char UTh[1024], UTl[1024];  // bf16 [j=16][c2=32],  off ^= ((j&3)<<4)
  int l = threadIdx.x;
  int bh = blockIdx.x & 7, js = blockIdx.x >> 3;   // XCD swizzle: 16 dv-slices of one bh share an L2
  int b = bh>>2, h = bh&3;
  int lr = l & 15, lk = l >> 4;
  int jb = js*16;
  float4 z4 = make_float4(0.f,0.f,0.f,0.f);
  #pragma unroll
  for(int i=0;i<8;i++){ ((float4*)STh)[l+i*64] = z4; ((float4*)STl)[l+i*64] = z4; }
  LDS_FENCE();
  f32x4 Sacc[16];
  #pragma unroll
  for(int i=0;i<16;i++) Sacc[i] = f32x4{0.f,0.f,0.f,0.f};
  const int Xst = (lr&7)<<4;   // ST row swizzle (bits 4-6 of FULL in-row byte offset, rule #21)
  const int Xut = (lr&3)<<4;   // UT row swizzle (bits 4-5)
  const bf16* wp  = wFb + (size_t)bh*NCH*8192;
  const bf16* up  = uFb + (size_t)bh*NCH*8192;
  const bf16* kp  = kTb + (size_t)bh*NCH*8192;
  const bf16* aph = aFb + (size_t)bh*NCH*1024;
  const bf16* apl = aFl + (size_t)bh*NCH*1024;
  const bf16* qp  = qn + (size_t)b*LL*HH + h*256;
  // prefetch registers (chunk 0)
  s16x8 Wr[16], Qr[16], Kr[16], A0h, A1h, A0l, A1l;
  bf16 Ur[8];
  #pragma unroll
  for(int t8=0;t8<8;t8++){
    Wr[t8]   = ldg8(wp + lr*256      + t8*32 + lk*8);
    Wr[8+t8] = ldg8(wp + (16+lr)*256 + t8*32 + lk*8);
    Qr[t8]   = ldg8(qp + (size_t)lr*HH      + t8*32 + lk*8);
    Qr[8+t8] = ldg8(qp + (size_t)(16+lr)*HH + t8*32 + lk*8);
  }
  #pragma unroll
  for(int dt=0;dt<16;dt++) Kr[dt] = ldg8(kp + (dt*16+lr)*32 + lk*8);
  A0h = ldg8(aph + lr*32 + lk*8); A1h = ldg8(aph + (16+lr)*32 + lk*8);
  A0l = ldg8(apl + lr*32 + lk*8); A1l = ldg8(apl + (16+lr)*32 + lk*8);
  #pragma unroll
  for(int r8=0;r8<8;r8++){
    int rr = (r8>>2)*16 + lk*4 + (r8&3);
    Ur[r8] = up[(size_t)rr*256 + jb + lr];
  }
  for(int ci=0; ci<NCH; ci++){
    size_t nxw = (ci<NCH-1)? 8192 : 0;            // next-chunk strides (clamped at tail)
    size_t nxa = (ci<NCH-1)? 1024 : 0;
    size_t nxq = (ci<NCH-1)? (size_t)32*HH : 0;
    // ---- Phase 1: ST fragments to regs, then the 64-MFMA block
    s16x8 sth[8], stl[8];
    #pragma unroll
    for(int t8=0;t8<8;t8++){
      int ro = lr*512 + ((t8*64 + lk*16) ^ Xst);
      sth[t8] = *(const s16x8*)(STh + ro);
      stl[t8] = *(const s16x8*)(STl + ro);
    }
    f32x4 wh0={0.f,0.f,0.f,0.f}, wl0=wh0, wh1=wh0, wl1=wh0;
    f32x4 qh0=wh0, ql0=wh0, qh1=wh0, ql1=wh0;
    #pragma unroll
    for(int t8=0;t8<8;t8++){
      wh0 = mfma16(Wr[t8],   sth[t8], wh0); wl0 = mfma16(Wr[t8],   stl[t8], wl0);
      wh1 = mfma16(Wr[8+t8], sth[t8], wh1); wl1 = mfma16(Wr[8+t8], stl[t8], wl1);
      qh0 = mfma16(Qr[t8],   sth[t8], qh0); ql0 = mfma16(Qr[t8],   stl[t8], ql0);
      qh1 = mfma16(Qr[8+t8], sth[t8], qh1); ql1 = mfma16(Qr[8+t8], stl[t8], ql1);
    }
    f32x4 ws0 = wh0+wl0, ws1 = wh1+wl1;
    f32x4 qs0 = qh0+ql0, qs1 = qh1+ql1;
    // prefetch next W,Q (regs fully consumed above)
    #pragma unroll
    for(int t8=0;t8<8;t8++){
      Wr[t8]   = ldg8(wp + nxw + lr*256      + t8*32 + lk*8);
      Wr[8+t8] = ldg8(wp + nxw + (16+lr)*256 + t8*32 + lk*8);
      Qr[t8]   = ldg8(qp + nxq + (size_t)lr*HH      + t8*32 + lk*8);
      Qr[8+t8] = ldg8(qp + nxq + (size_t)(16+lr)*HH + t8*32 + lk*8);
    }
    // ---- Phase 2: u_t = u - wS -> UT hi/lo (lane holds (c=ct*16+lk*4+r, j=lr))
    #pragma unroll
    for(int ct=0;ct<2;ct++){
      f32x4 w = ct? ws1 : ws0;
      bf16x4 hh, llo;
      #pragma unroll
      for(int r=0;r<4;r++){
        float v = b2f(Ur[ct*4+r]) - w[r];
        bf16 hb = f2b(v); hh[r]=hb; llo[r]=f2b(v-(float)hb);
      }
      int utw = lr*64 + ((ct*32 + lk*8) ^ Xut);
      *(bf16x4*)(UTh+utw)=hh; *(bf16x4*)(UTl+utw)=llo;
    }
    #pragma unroll
    for(int r8=0;r8<8;r8++){
      int rr = (r8>>2)*16 + lk*4 + (r8&3);
      Ur[r8] = up[nxw + (size_t)rr*256 + jb + lr];
    }
    LDS_FENCE();   // cross-lane UT handoff (single wave: lgkmcnt suffices, no barrier)
    int utR = lr*64 + ((lk*16) ^ Xut);
    s16x8 th = *(const s16x8*)(UTh + utR);
    s16x8 tl = *(const s16x8*)(UTl + utR);
    // ---- Phase 3: o = qS + attn@u_t
    qs0 = mfma16(A0h, th, qs0); qs0 = mfma16(A0h, tl, qs0); qs0 = mfma16(A0l, th, qs0);
    qs1 = mfma16(A1h, th, qs1); qs1 = mfma16(A1h, tl, qs1); qs1 = mfma16(A1l, th, qs1);
    bf16* dp = delta + ((size_t)(b*LL + ci*32))*HH + h*256 + jb + lr;
    #pragma unroll
    for(int ct=0;ct<2;ct++){
      f32x4 o = ct? qs1 : qs0;
      #pragma unroll
      for(int r=0;r<4;r++) dp[(size_t)(ct*16 + lk*4 + r)*HH] = f2b(o[r]);
    }
    A0h = ldg8(aph + nxa + lr*32 + lk*8); A1h = ldg8(aph + nxa + (16+lr)*32 + lk*8);
    A0l = ldg8(apl + nxa + lr*32 + lk*8); A1l = ldg8(apl + nxa + (16+lr)*32 + lk*8);
    // ---- Phase 4: S[dk][j] += k^T @ u_t
    #pragma unroll
    for(int dt=0;dt<16;dt++){
      Sacc[dt] = mfma16(Kr[dt], th, Sacc[dt]);
      Sacc[dt] = mfma16(Kr[dt], tl, Sacc[dt]);
    }
    #pragma unroll
    for(int dt=0;dt<16;dt++) Kr[dt] = ldg8(kp + nxw + (size_t)(dt*16+lr)*32 + lk*8);
    // ---- Phase 5: restage S -> LDS bf16 hi/lo
    #pragma unroll
    for(int dt=0;dt<16;dt++){
      bf16x4 hh, llo;
      #pragma unroll
      for(int r=0;r<4;r++){
        float v = Sacc[dt][r];
        bf16 hb=f2b(v); hh[r]=hb; llo[r]=f2b(v-(float)hb);
      }
      int stw = lr*512 + ((dt*32 + lk*8) ^ Xst);
      *(bf16x4*)(STh+stw)=hh; *(bf16x4*)(STl+stw)=llo;
    }
    LDS_FENCE();   // S restage visible before next chunk's phase-1 reads
    wp += nxw; up += nxw; kp += nxw; aph += nxa; apl += nxa; qp += nxq;
  }
}

// ---------------- FIR convs + gated fusion + RMSNorm ----------------
__global__ __launch_bounds__(256) void k_fuse(const bf16* __restrict__ vv, const bf16* __restrict__ delta,
    const float* __restrict__ fw, const float* __restrict__ fsw, const float* __restrict__ flw,
    const float* __restrict__ rmsw, bf16* __restrict__ fused){
  __shared__ float red[4][8];
  int tx = threadIdx.x, head = blockIdx.y, b = blockIdx.z; int l0 = blockIdx.x*64;
  int wv = tx>>6, lane = tx&63;
  int c = head*256 + tx;
  const bf16* vp = vv + (size_t)b*LL*HH + c;
  float fs[7], fl[64];
  #pragma unroll
  for(int j=0;j<7;j++) fs[j] = fsw[(size_t)c*7+j];
  #pragma unroll
  for(int j=0;j<64;j++) fl[j] = flw[(size_t)c*64+j];
  float win[64];
  #pragma unroll
  for(int i=0;i<63;i++){ int l=l0-63+i; win[i] = (l>=0)? b2f(vp[(size_t)l*HH]) : 0.f; }
  float rw = rmsw[tx];
  for(int g=0; g<8; g++){
    float oo[8], sq[8];
    #pragma unroll
    for(int i=0;i<8;i++){
      int s = g*8+i; int l = l0+s;
      win[(s+63)&63] = b2f(vp[(size_t)l*HH]);
      float ll2 = 0.f;
      #pragma unroll
      for(int tp=0;tp<64;tp++) ll2 += fl[tp]*win[(s+tp)&63];
      float ls = 0.f;
      #pragma unroll
      for(int tp=0;tp<7;tp++) ls += fs[tp]*win[(s+57+tp)&63];
      float dl = b2f(delta[(size_t)(b*LL+l)*HH + c]);
      float vh = win[(s+63)&63];
      const float* fp = fw + (size_t)(b*LL+l)*16 + head*4;
      float o = fp[0]*ls + fp[1]*ll2 + fp[2]*dl + fp[3]*vh;
      oo[i]=o; sq[i]=o*o;
    }
    #pragma unroll
    for(int off=32;off>=1;off>>=1)
      #pragma unroll
      for(int i=0;i<8;i++) sq[i] += __shfl_down(sq[i],off,64);
    if(lane==0){
      #pragma unroll
      for(int i=0;i<8;i++) red[wv][i]=sq[i];
    }
    __syncthreads();
    float tot[8];
    #pragma unroll
    for(int i=0;i<8;i++) tot[i]=red[0][i]+red[1][i]+red[2][i]+red[3][i];
    __syncthreads();
    #pragma unroll
    for(int i=0;i<8;i++){
      int l = l0+g*8+i;
      fused[(size_t)(b*LL+l)*HH + c] = f2b(oo[i]*rsqrtf(tot[i]*(1.f/256.f)+1e-5f)*rw);
    }
  }
}

extern "C" void kernel_launch(void* const* d_in, const int* in_sizes, int n_in,
                              void* d_out, int out_size, void* d_ws, size_t ws_size,
                              hipStream_t stream){
  const float* hs  =(const float*)d_in[0];
  const float* Wq  =(const float*)d_in[1];
  const float* Wk  =(const float*)d_in[2];
  const float* Wv  =(const float*)d_in[3];
  const float* Wb  =(const float*)d_in[4];
  const float* cqw =(const float*)d_in[5];
  const float* ckw =(const float*)d_in[6];
  const float* cvw =(const float*)d_in[7];
  const float* fsw =(const float*)d_in[8];
  const float* flw =(const float*)d_in[9];
  const float* Wf1 =(const float*)d_in[10];
  const float* bf1 =(const float*)d_in[11];
  const float* Wf2 =(const float*)d_in[12];
  const float* bf2v=(const float*)d_in[13];
  const float* rmsw=(const float*)d_in[14];
  const float* Wo  =(const float*)d_in[15];

  char* ws = (char*)d_ws;
  size_t off = 0;
  auto alloc = [&](size_t bytes)->char*{
    char* p = ws + off; off = (off + bytes + 255) & ~(size_t)255; return p;
  };
  bf16* pre   = (bf16*)alloc(8192ull*1024*2);   // q/k/v pre-conv (sequential); later kTb; later fusedb
  bf16* qn    = (bf16*)alloc(8192ull*1024*2);
  bf16* kn    = (bf16*)alloc(8192ull*1024*2);
  bf16* vvb   = (bf16*)alloc(8192ull*1024*2);
  float* beta = (float*)alloc(8192ull*4*4);
  bf16* uFb   = (bf16*)alloc(8ull*128*8192*2);  // h1 aliases uFb+wFb (32MB) before k_pre2
  bf16* wFb   = (bf16*)alloc(8ull*128*8192*2);
  bf16* aFb   = (bf16*)alloc(8ull*128*1024*4);  // hi (2MB) + lo (2MB) attn, bf16
  float* fw   = (float*)alloc(8192ull*16*4);
  bf16* aFl   = aFb + 8ull*128*1024;
  bf16* h1    = uFb;                            // dead once fw extracted
  bf16* kTb   = pre;                            // pre dead after conv-v; dead again before k_fuse
  bf16* dlt   = (bf16*)d_out;                   // first 16MB of the 32MB f32 out; dead before final GEMM
  bf16* fusedb= pre;
  float* outb = (float*)d_out;
  // aliased staging (no extra workspace):
  //  - hsb (bf16 hs, 16MB): vvb-space — vvb is only written by conv-v, the LAST hs consumer ran
  //  - WT(Wf1) hi 4MB: qn-space (qn written by conv-q, after the gate GEMM)
  //  - WT(Wq/Wk/Wv/Wo) hi 2MB: uFb-space (dead between k_gate and k_pre2, and after k_scan4)
  bf16* hsb  = vvb;
  bf16* WT1h = qn;
  bf16* WTh  = uFb;

  dim3 b256(256);
  // hs -> bf16 once
  k_h2b<<<dim3(4096), b256, 0, stream>>>(hs, hsb);
  // gate path FIRST (h1 aliases uFb/wFb; WT(Wf1) lives in qn-space)
  k_wT<<<dim3(64,32), b256, 0, stream>>>(Wf1, WT1h, 1024, 2048);
  k_gemm_m2<1,0><<<dim3(16,64), b256, 0, stream>>>(hsb, WT1h, bf1, h1, 8192, 2048, 1024);
  k_gate<<<dim3(2048), b256, 0, stream>>>(h1, Wf2, bf2v, fw);
  // q path (WT in uFb-space, dead until k_pre2)
  k_wT<<<dim3(32,32), b256, 0, stream>>>(Wq, WTh, 1024, 1024);
  k_gemm_m2<0,0><<<dim3(8,64), b256, 0, stream>>>(hsb, WTh, nullptr, pre, 8192, 1024, 1024);
  k_conv4<<<dim3(64,4,2), b256, 0, stream>>>(pre, cqw, qn, 1);
  // k path
  k_wT<<<dim3(32,32), b256, 0, stream>>>(Wk, WTh, 1024, 1024);
  k_gemm_m2<0,0><<<dim3(8,64), b256, 0, stream>>>(hsb, WTh, nullptr, pre, 8192, 1024, 1024);
  k_conv4<<<dim3(64,4,2), b256, 0, stream>>>(pre, ckw, kn, 1);
  // v path (last hsb use, then conv-v overwrites hsb with vvb)
  k_wT<<<dim3(32,32), b256, 0, stream>>>(Wv, WTh, 1024, 1024);
  k_gemm_m2<0,0><<<dim3(8,64), b256, 0, stream>>>(hsb, WTh, nullptr, pre, 8192, 1024, 1024);
  k_conv4<<<dim3(64,4,2), b256, 0, stream>>>(pre, cvw, vvb, 0);
  // beta (reads hs f32)
  k_beta<<<dim3(2048), b256, 0, stream>>>(hs, Wb, beta);
  // delta rule (overwrites uFb/wFb — WT dead)
  k_pre2<<<dim3(128,8), b256, 0, stream>>>(qn, kn, vvb, beta, uFb, wFb, aFb, aFl, kTb);
  k_scan4<<<dim3(128), dim3(64), 0, stream>>>(qn, wFb, uFb, kTb, aFb, aFl, dlt);
  // fuse + output projection (f32 out); WT(Wo) in uFb-space (dead after scan)
  k_fuse<<<dim3(64,4,2), b256, 0, stream>>>(vvb, dlt, fw, fsw, flw, rmsw, fusedb);
  k_wT<<<dim3(32,32), b256, 0, stream>>>(Wo, WTh, 1024, 1024);
  k_gemm_m2<0,1><<<dim3(8,64), b256, 0, stream>>>(fusedb, WTh, nullptr, outb, 8192, 1024, 1024);

  (void)in_sizes; (void)n_in; (void)out_size; (void)ws_size;
}